// Round 2
// baseline (1718.030 us; speedup 1.0000x reference)
//
#include <hip/hip_runtime.h>
#include <hip/hip_bf16.h>
#include <math.h>

typedef __attribute__((ext_vector_type(8))) short short8;
typedef __attribute__((ext_vector_type(4))) float f32x4;
typedef unsigned short u16;
typedef unsigned int u32;

// ---------- helpers ----------
__device__ __forceinline__ float bf2f(u16 u) {
    union { u32 i; float f; } x; x.i = ((u32)u) << 16; return x.f;
}
__device__ __forceinline__ u16 f2bf(float f) {
    union { float f; u32 i; } u; u.f = f;
    u32 r = u.i + 0x7fffu + ((u.i >> 16) & 1u);   // RNE
    return (u16)(r >> 16);
}
__device__ __forceinline__ float dotpair(u32 a, u32 b) {
    union { u32 i; float f; } alo, ahi, blo, bhi;
    alo.i = a << 16; ahi.i = a & 0xffff0000u;
    blo.i = b << 16; bhi.i = b & 0xffff0000u;
    return alo.f * blo.f + ahi.f * bhi.f;
}
__device__ __forceinline__ float bdot16(const u16* a, const u16* b) {
    uint4 a0 = *(const uint4*)a, a1 = *(const uint4*)(a + 8);
    uint4 b0 = *(const uint4*)b, b1 = *(const uint4*)(b + 8);
    float s = 0.f;
    s += dotpair(a0.x, b0.x); s += dotpair(a0.y, b0.y);
    s += dotpair(a0.z, b0.z); s += dotpair(a0.w, b0.w);
    s += dotpair(a1.x, b1.x); s += dotpair(a1.y, b1.y);
    s += dotpair(a1.z, b1.z); s += dotpair(a1.w, b1.w);
    return s;
}

// ---------- weight prep (f32 in, bf16 hi/lo out, transposed) ----------
// out_hi/lo[m][128] = split(in[k][m]), in is [128][M] row-major
__global__ void prep_wt_k(const float* __restrict__ in, u16* __restrict__ hi,
                          u16* __restrict__ lo, int M) {
    int idx = blockIdx.x * 256 + threadIdx.x;
    if (idx >= M * 128) return;
    int m = idx >> 7, k = idx & 127;
    float w = in[k * M + m];
    u16 h = f2bf(w);
    hi[idx] = h;
    lo[idx] = f2bf(w - bf2f(h));
}

// fused (w @ blockdiag(rel)) transposed+split: j = l*4 + dir*2 + kv
__global__ void prep_fused_k(const float* kw_q, const float* kw_a,
                             const float* vw_q, const float* vw_a,
                             const float* a_rel, const float* m_rel,
                             u16* __restrict__ hi, u16* __restrict__ lo) {
    int j = blockIdx.y;
    int l = j >> 2, dir = (j >> 1) & 1, kv = j & 1;
    const float* w = kv ? (dir ? vw_a : vw_q) : (dir ? kw_a : kw_q);
    w += l * 16384;
    const float* rel = (kv ? m_rel : a_rel) + (l * 2 + dir) * 2048;
    int idx = blockIdx.x * 256 + threadIdx.x;       // 16384
    int m = idx >> 7, k = idx & 127;
    int h = m >> 4, f = m & 15;
    float s = 0.f;
#pragma unroll
    for (int d = 0; d < 16; d++)
        s += w[k * 128 + h * 16 + d] * rel[(h * 16 + d) * 16 + f];
    u16 hh = f2bf(s);
    hi[j * 16384 + m * 128 + k] = hh;
    lo[j * 16384 + m * 128 + k] = f2bf(s - bf2f(hh));
}

__global__ void prep_fbias_k(const float* kb_q, const float* kb_a,
                             const float* vb_q, const float* vb_a,
                             const float* a_rel, const float* m_rel,
                             float* __restrict__ outB) {
    int idx = blockIdx.x * 256 + threadIdx.x;       // 1024
    if (idx >= 1024) return;
    int j = idx >> 7, m = idx & 127;
    int l = j >> 2, dir = (j >> 1) & 1, kv = j & 1;
    int h = m >> 4, f = m & 15;
    const float* b = kv ? (dir ? vb_a : vb_q) : (dir ? kb_a : kb_q);
    b += l * 128;
    const float* rel = (kv ? m_rel : a_rel) + (l * 2 + dir) * 2048;
    float s = 0.f;
#pragma unroll
    for (int d = 0; d < 16; d++)
        s += b[h * 16 + d] * rel[(h * 16 + d) * 16 + f];
    outB[idx] = s;
}

// ---------- CSR build ----------
__global__ void hist_k(const int* __restrict__ dst, int E, int* __restrict__ deg) {
    int i = blockIdx.x * 256 + threadIdx.x;
    if (i < E) atomicAdd(&deg[dst[i]], 1);
}
__global__ void scanA_k(const int* __restrict__ deg, int* __restrict__ incl,
                        int* __restrict__ bsum, int n) {
    __shared__ int s[256];
    int i = blockIdx.x * 256 + threadIdx.x;
    int v = (i < n) ? deg[i] : 0;
    s[threadIdx.x] = v;
    __syncthreads();
    for (int off = 1; off < 256; off <<= 1) {
        int t = (threadIdx.x >= off) ? s[threadIdx.x - off] : 0;
        __syncthreads();
        s[threadIdx.x] += t;
        __syncthreads();
    }
    if (i < n) incl[i] = s[threadIdx.x];
    if (threadIdx.x == 255) bsum[blockIdx.x] = s[255];
}
__global__ void scanB_k(int* __restrict__ bsum, int nb) {   // nb <= 256
    __shared__ int s[256];
    int v = (threadIdx.x < nb) ? bsum[threadIdx.x] : 0;
    s[threadIdx.x] = v;
    __syncthreads();
    for (int off = 1; off < 256; off <<= 1) {
        int t = (threadIdx.x >= off) ? s[threadIdx.x - off] : 0;
        __syncthreads();
        s[threadIdx.x] += t;
        __syncthreads();
    }
    if (threadIdx.x < nb) bsum[threadIdx.x] = s[threadIdx.x] - v;  // exclusive
}
__global__ void scanC_k(const int* __restrict__ incl, const int* __restrict__ deg,
                        const int* __restrict__ bsum, int* __restrict__ offs,
                        int* __restrict__ cursor, int n, int Etot) {
    int i = blockIdx.x * 256 + threadIdx.x;
    if (i < n) {
        int o = incl[i] - deg[i] + bsum[blockIdx.x];
        offs[i] = o;
        cursor[i] = o;
    }
    if (i == 0) offs[n] = Etot;
}
__global__ void scatter_k(const int* __restrict__ dst, int E,
                          int* __restrict__ cursor, int* __restrict__ eid) {
    int e = blockIdx.x * 256 + threadIdx.x;
    if (e < E) {
        int p = atomicAdd(&cursor[dst[e]], 1);
        eid[p] = e;
    }
}

// ---------- edge phase ----------
__global__ void alpha_k(const int* __restrict__ ei, int E,
                        const u16* __restrict__ kt, const u16* __restrict__ qd,
                        const float* __restrict__ pr, float* __restrict__ alpha) {
    int t = blockIdx.x * 256 + threadIdx.x;
    if (t >= E * 8) return;
    int e = t >> 3, h = t & 7;
    int s = ei[e], d = ei[E + e];
    float acc = bdot16(kt + (size_t)s * 128 + h * 16, qd + (size_t)d * 128 + h * 16);
    alpha[t] = acc * pr[h] * 0.25f;   // SCALE = 1/sqrt(16)
}

__global__ void softmax_k(const int* __restrict__ offs, const int* __restrict__ eid,
                          float* __restrict__ alpha, int n) {
    int t = blockIdx.x * 256 + threadIdx.x;
    if (t >= n * 8) return;
    int node = t >> 3, h = t & 7;
    int s0 = offs[node], s1 = offs[node + 1];
    if (s0 == s1) return;
    float m = -1e30f;
    for (int j = s0; j < s1; j++) m = fmaxf(m, alpha[eid[j] * 8 + h]);
    float den = 0.f;
    for (int j = s0; j < s1; j++) {
        float e = __expf(alpha[eid[j] * 8 + h] - m);
        alpha[eid[j] * 8 + h] = e;
        den += e;
    }
    float inv = 1.f / den;
    for (int j = s0; j < s1; j++) alpha[eid[j] * 8 + h] *= inv;
}

// 2 nodes x 128 channels per block: msg[n][c] = gelu( sum_e attn*vt[src][c] )
__global__ void aggregate_k(const int* __restrict__ offs, const int* __restrict__ eid,
                            const int* __restrict__ eisrc, const float* __restrict__ alpha,
                            const u16* __restrict__ vt, float* __restrict__ msg, int n) {
    int node = blockIdx.x * 2 + (threadIdx.x >> 7);
    if (node >= n) return;
    int c = threadIdx.x & 127;
    int h = c >> 4;
    float acc = 0.f;
    int s0 = offs[node], s1 = offs[node + 1];
    for (int j = s0; j < s1; j++) {
        int e = eid[j];
        float w = alpha[e * 8 + h];
        int s = eisrc[e];
        acc += w * bf2f(vt[(size_t)s * 128 + c]);
    }
    float g = 0.5f * acc * (1.f + erff(acc * 0.70710678118654752f));
    msg[(size_t)node * 128 + c] = g;
}

// ---------- register GEMM: Y[N][MOUT] = act(X[N][128] @ W + b) ----------
// X f32; W pre-transposed+split bf16 hi/lo [MOUT][128]; 3-MFMA split => ~f32 accuracy.
// ACT: 0 none, 1 relu. SKIP: y = g*y + (1-g)*skipx. OUTBF16: store bf16 else f32.
template <int MOUT, int ACT, bool SKIP, bool OUTBF16>
__global__ __launch_bounds__(256) void gemm_rr(
    const float* __restrict__ X, const u16* __restrict__ Whi, const u16* __restrict__ Wlo,
    const float* __restrict__ bias, const float* skipx, const float* gate,
    void* Y, int N) {
    int wave = threadIdx.x >> 6, lane = threadIdx.x & 63;
    int lr = lane & 15, kg = lane >> 4;
    int arow = blockIdx.x * 64 + wave * 16 + lr;

    // load A row fragment: 32 floats (k = ks*32 + kg*8 + j)
    float a[32];
#pragma unroll
    for (int ks = 0; ks < 4; ks++) {
        float4 v0 = make_float4(0.f, 0.f, 0.f, 0.f), v1 = v0;
        if (arow < N) {
            const float* p = X + (size_t)arow * 128 + ks * 32 + kg * 8;
            v0 = *(const float4*)p;
            v1 = *(const float4*)(p + 4);
        }
        a[ks * 8 + 0] = v0.x; a[ks * 8 + 1] = v0.y; a[ks * 8 + 2] = v0.z; a[ks * 8 + 3] = v0.w;
        a[ks * 8 + 4] = v1.x; a[ks * 8 + 5] = v1.y; a[ks * 8 + 6] = v1.z; a[ks * 8 + 7] = v1.w;
    }
    short8 ahi[4], alo[4];
#pragma unroll
    for (int ks = 0; ks < 4; ks++) {
#pragma unroll
        for (int j = 0; j < 8; j++) {
            float w = a[ks * 8 + j];
            u16 h = f2bf(w);
            ahi[ks][j] = (short)h;
            alo[ks][j] = (short)f2bf(w - bf2f(h));
        }
    }

    constexpr int NCT = MOUT / 16;
    f32x4 acc[NCT];
#pragma unroll
    for (int i = 0; i < NCT; i++) acc[i] = f32x4{0.f, 0.f, 0.f, 0.f};

#pragma unroll
    for (int ks = 0; ks < 4; ks++) {
#pragma unroll
        for (int ct = 0; ct < NCT; ct++) {
            size_t wof = (size_t)(ct * 16 + lr) * 128 + ks * 32 + kg * 8;
            short8 whi = *(const short8*)(Whi + wof);
            short8 wlo = *(const short8*)(Wlo + wof);
            acc[ct] = __builtin_amdgcn_mfma_f32_16x16x32_bf16(ahi[ks], whi, acc[ct], 0, 0, 0);
            acc[ct] = __builtin_amdgcn_mfma_f32_16x16x32_bf16(alo[ks], whi, acc[ct], 0, 0, 0);
            acc[ct] = __builtin_amdgcn_mfma_f32_16x16x32_bf16(ahi[ks], wlo, acc[ct], 0, 0, 0);
        }
    }

    float g = 1.f, gi = 0.f;
    if (SKIP) {
        float sk = gate[0];
        g = 1.f / (1.f + __expf(-sk));
        gi = 1.f - g;
    }
    int crow0 = blockIdx.x * 64 + wave * 16 + kg * 4;
#pragma unroll
    for (int ct = 0; ct < NCT; ct++) {
        int col = ct * 16 + lr;
        float bcol = bias[col];
#pragma unroll
        for (int r = 0; r < 4; r++) {
            int gr = crow0 + r;
            if (gr < N) {
                float v = acc[ct][r] + bcol;
                if (ACT == 1) v = fmaxf(v, 0.f);
                if (SKIP) v = g * v + gi * skipx[(size_t)gr * 128 + col];
                if (OUTBF16) ((u16*)Y)[(size_t)gr * MOUT + col] = f2bf(v);
                else         ((float*)Y)[(size_t)gr * MOUT + col] = v;
            }
        }
    }
}

// ---------- launch ----------
extern "C" void kernel_launch(void* const* d_in, const int* in_sizes, int n_in,
                              void* d_out, int out_size, void* d_ws, size_t ws_size,
                              hipStream_t stream) {
    const int NQ = in_sizes[0] / 128;
    const int NA = in_sizes[1] / 128;
    const int Eqa = in_sizes[29] / 2;
    const int Eaq = in_sizes[30] / 2;
    const int NM = (NQ > NA) ? NQ : NA;
    const int EM = (Eqa > Eaq) ? Eqa : Eaq;

    const float* x_q     = (const float*)d_in[0];
    const float* x_a     = (const float*)d_in[1];
    const float* lin0_wq = (const float*)d_in[2];
    const float* lin0_bq = (const float*)d_in[3];
    const float* lin0_wa = (const float*)d_in[4];
    const float* lin0_ba = (const float*)d_in[5];
    const float* kw_q = (const float*)d_in[6];
    const float* kb_q = (const float*)d_in[7];
    const float* qw_q = (const float*)d_in[8];
    const float* qb_q = (const float*)d_in[9];
    const float* vw_q = (const float*)d_in[10];
    const float* vb_q = (const float*)d_in[11];
    const float* aw_q = (const float*)d_in[12];
    const float* ab_q = (const float*)d_in[13];
    const float* kw_a = (const float*)d_in[14];
    const float* kb_a = (const float*)d_in[15];
    const float* qw_a = (const float*)d_in[16];
    const float* qb_a = (const float*)d_in[17];
    const float* vw_a = (const float*)d_in[18];
    const float* vb_a = (const float*)d_in[19];
    const float* aw_a = (const float*)d_in[20];
    const float* ab_a = (const float*)d_in[21];
    const float* skip_q = (const float*)d_in[22];
    const float* skip_a = (const float*)d_in[23];
    const float* a_rel = (const float*)d_in[24];
    const float* m_rel = (const float*)d_in[25];
    const float* p_rel = (const float*)d_in[26];
    const float* lin_w = (const float*)d_in[27];
    const float* lin_b = (const float*)d_in[28];
    const int* ei_qa = (const int*)d_in[29];
    const int* ei_aq = (const int*)d_in[30];

    // ---- workspace layout ----
    size_t off = 0;
    auto alloc = [&](size_t bytes) -> void* {
        void* p = (char*)d_ws + off;
        off += (bytes + 255) & ~(size_t)255;
        return p;
    };
    float* xq   = (float*)alloc((size_t)NQ * 128 * 4);
    float* xa   = (float*)alloc((size_t)NA * 128 * 4);
    float* msgq = (float*)alloc((size_t)NQ * 128 * 4);
    float* msga = (float*)alloc((size_t)NA * 128 * 4);
    u16* kt   = (u16*)alloc((size_t)NM * 128 * 2);
    u16* vt   = (u16*)alloc((size_t)NM * 128 * 2);
    u16* qd   = (u16*)alloc((size_t)NM * 128 * 2);
    float* alpha = (float*)alloc((size_t)EM * 8 * 4);   // also int scratch for scans
    int* offs_a = (int*)alloc((size_t)(NA + 1) * 4);
    int* offs_q = (int*)alloc((size_t)(NQ + 1) * 4);
    int* eid_a  = (int*)alloc((size_t)Eqa * 4);
    int* eid_q  = (int*)alloc((size_t)Eaq * 4);
    int* deg    = (int*)alloc((size_t)NM * 4);
    int* cursor = (int*)alloc((size_t)NM * 4);
    int* bsum   = (int*)alloc(1024);
    // weight buffers: hi+lo pairs
    u16* W_LIN0Q_h = (u16*)alloc(16384 * 2); u16* W_LIN0Q_l = (u16*)alloc(16384 * 2);
    u16* W_LIN0A_h = (u16*)alloc(16384 * 2); u16* W_LIN0A_l = (u16*)alloc(16384 * 2);
    u16* W_QQ_h = (u16*)alloc(2 * 16384 * 2); u16* W_QQ_l = (u16*)alloc(2 * 16384 * 2);
    u16* W_QA_h = (u16*)alloc(2 * 16384 * 2); u16* W_QA_l = (u16*)alloc(2 * 16384 * 2);
    u16* W_AQ_h = (u16*)alloc(2 * 16384 * 2); u16* W_AQ_l = (u16*)alloc(2 * 16384 * 2);
    u16* W_AA_h = (u16*)alloc(2 * 16384 * 2); u16* W_AA_l = (u16*)alloc(2 * 16384 * 2);
    u16* W_F_h  = (u16*)alloc(8 * 16384 * 2); u16* W_F_l  = (u16*)alloc(8 * 16384 * 2);
    u16* W_LIN_h = (u16*)alloc(8192 * 2);     u16* W_LIN_l = (u16*)alloc(8192 * 2);
    float* BF = (float*)alloc(8 * 128 * 4);
    (void)ws_size; (void)n_in; (void)out_size;

    dim3 B(256);
    auto T = [&](const float* src, u16* hi, u16* lo, int M) {
        prep_wt_k<<<dim3((M * 128 + 255) / 256), B, 0, stream>>>(src, hi, lo, M);
    };
    T(lin0_wq, W_LIN0Q_h, W_LIN0Q_l, 128);
    T(lin0_wa, W_LIN0A_h, W_LIN0A_l, 128);
    for (int l = 0; l < 2; l++) {
        T(qw_q + l * 16384, W_QQ_h + l * 16384, W_QQ_l + l * 16384, 128);
        T(qw_a + l * 16384, W_QA_h + l * 16384, W_QA_l + l * 16384, 128);
        T(aw_q + l * 16384, W_AQ_h + l * 16384, W_AQ_l + l * 16384, 128);
        T(aw_a + l * 16384, W_AA_h + l * 16384, W_AA_l + l * 16384, 128);
    }
    T(lin_w, W_LIN_h, W_LIN_l, 64);
    prep_fused_k<<<dim3(64, 8), B, 0, stream>>>(kw_q, kw_a, vw_q, vw_a, a_rel, m_rel, W_F_h, W_F_l);
    prep_fbias_k<<<dim3(4), B, 0, stream>>>(kb_q, kb_a, vb_q, vb_a, a_rel, m_rel, BF);

    // CSR build (keyed by dst = row 1 of ei)
    auto buildCSR = [&](const int* eibase, int Etot, int n, int* offs, int* eid) {
        const int* dstRow = eibase + Etot;
        int gE = (Etot + 255) / 256, gN = (n + 255) / 256;
        hipMemsetAsync(deg, 0, (size_t)n * 4, stream);
        hist_k<<<dim3(gE), B, 0, stream>>>(dstRow, Etot, deg);
        scanA_k<<<dim3(gN), B, 0, stream>>>(deg, (int*)alpha, bsum, n);
        scanB_k<<<dim3(1), B, 0, stream>>>(bsum, gN);
        scanC_k<<<dim3(gN), B, 0, stream>>>((int*)alpha, deg, bsum, offs, cursor, n, Etot);
        scatter_k<<<dim3(gE), B, 0, stream>>>(dstRow, Etot, cursor, eid);
    };
    buildCSR(ei_qa, Eqa, NA, offs_a, eid_a);
    buildCSR(ei_aq, Eaq, NQ, offs_q, eid_q);

    // GEMM dispatch helpers
    auto Glin0 = [&](const float* X, const u16* wh, const u16* wl, const float* b, float* Y, int N) {
        gemm_rr<128, 1, false, false><<<dim3((N + 63) / 64), B, 0, stream>>>(X, wh, wl, b, nullptr, nullptr, Y, N);
    };
    auto Gbf = [&](const float* X, const u16* wh, const u16* wl, const float* b, u16* Y, int N) {
        gemm_rr<128, 0, false, true><<<dim3((N + 63) / 64), B, 0, stream>>>(X, wh, wl, b, nullptr, nullptr, Y, N);
    };
    auto Gskip = [&](const float* X, const u16* wh, const u16* wl, const float* b,
                     const float* skipx, const float* gate, float* Y, int N) {
        gemm_rr<128, 0, true, false><<<dim3((N + 63) / 64), B, 0, stream>>>(X, wh, wl, b, skipx, gate, Y, N);
    };
    auto Gfin = [&](const float* X, float* Y, int N) {
        gemm_rr<64, 0, false, false><<<dim3((N + 63) / 64), B, 0, stream>>>(X, W_LIN_h, W_LIN_l, lin_b, nullptr, nullptr, Y, N);
    };

    // input projections + relu
    Glin0(x_q, W_LIN0Q_h, W_LIN0Q_l, lin0_bq, xq, NQ);
    Glin0(x_a, W_LIN0A_h, W_LIN0A_l, lin0_ba, xa, NA);

    for (int l = 0; l < 2; l++) {
        // dir 0: question -> answer
        Gbf(xa, W_QA_h + l * 16384, W_QA_l + l * 16384, qb_a + l * 128, qd, NA);
        Gbf(xq, W_F_h + (l * 4 + 0) * 16384, W_F_l + (l * 4 + 0) * 16384, BF + (l * 4 + 0) * 128, kt, NQ);
        Gbf(xq, W_F_h + (l * 4 + 1) * 16384, W_F_l + (l * 4 + 1) * 16384, BF + (l * 4 + 1) * 128, vt, NQ);
        alpha_k<<<dim3((Eqa * 8 + 255) / 256), B, 0, stream>>>(ei_qa, Eqa, kt, qd, p_rel + (l * 2 + 0) * 8, alpha);
        softmax_k<<<dim3((NA * 8 + 255) / 256), B, 0, stream>>>(offs_a, eid_a, alpha, NA);
        aggregate_k<<<dim3((NA + 1) / 2), B, 0, stream>>>(offs_a, eid_a, ei_qa, alpha, vt, msga, NA);
        // dir 1: answer -> question
        Gbf(xq, W_QQ_h + l * 16384, W_QQ_l + l * 16384, qb_q + l * 128, qd, NQ);
        Gbf(xa, W_F_h + (l * 4 + 2) * 16384, W_F_l + (l * 4 + 2) * 16384, BF + (l * 4 + 2) * 128, kt, NA);
        Gbf(xa, W_F_h + (l * 4 + 3) * 16384, W_F_l + (l * 4 + 3) * 16384, BF + (l * 4 + 3) * 128, vt, NA);
        alpha_k<<<dim3((Eaq * 8 + 255) / 256), B, 0, stream>>>(ei_aq, Eaq, kt, qd, p_rel + (l * 2 + 1) * 8, alpha);
        softmax_k<<<dim3((NQ * 8 + 255) / 256), B, 0, stream>>>(offs_q, eid_q, alpha, NQ);
        aggregate_k<<<dim3((NQ + 1) / 2), B, 0, stream>>>(offs_q, eid_q, ei_aq, alpha, vt, msgq, NQ);
        // output projections + gated skip (per-element read-then-write, same thread)
        Gskip(msgq, W_AQ_h + l * 16384, W_AQ_l + l * 16384, ab_q + l * 128, xq, skip_q + l, xq, NQ);
        Gskip(msga, W_AA_h + l * 16384, W_AA_l + l * 16384, ab_a + l * 128, xa, skip_a + l, xa, NA);
    }

    // final linear into d_out (rows [0,NQ) question, [NQ,NQ+NA) answer), f32 out
    Gfin(xq, (float*)d_out, NQ);
    Gfin(xa, (float*)d_out + (size_t)NQ * 64, NA);
}

// Round 3
// 1191.274 us; speedup vs baseline: 1.4422x; 1.4422x over previous
//
#include <hip/hip_runtime.h>
#include <hip/hip_bf16.h>
#include <math.h>

typedef __attribute__((ext_vector_type(8))) short short8;
typedef __attribute__((ext_vector_type(4))) float f32x4;
typedef unsigned short u16;
typedef unsigned int u32;

// ---------- helpers ----------
__device__ __forceinline__ float bf2f(u16 u) {
    union { u32 i; float f; } x; x.i = ((u32)u) << 16; return x.f;
}
__device__ __forceinline__ u16 f2bf(float f) {
    union { float f; u32 i; } u; u.f = f;
    u32 r = u.i + 0x7fffu + ((u.i >> 16) & 1u);   // RNE
    return (u16)(r >> 16);
}
__device__ __forceinline__ float dotpair(u32 a, u32 b) {
    union { u32 i; float f; } alo, ahi, blo, bhi;
    alo.i = a << 16; ahi.i = a & 0xffff0000u;
    blo.i = b << 16; bhi.i = b & 0xffff0000u;
    return alo.f * blo.f + ahi.f * bhi.f;
}

// ---------- weight prep (f32 in, bf16 hi/lo out, transposed) ----------
__global__ void prep_wt_k(const float* __restrict__ in, u16* __restrict__ hi,
                          u16* __restrict__ lo, int M) {
    int idx = blockIdx.x * 256 + threadIdx.x;
    if (idx >= M * 128) return;
    int m = idx >> 7, k = idx & 127;
    float w = in[k * M + m];
    u16 h = f2bf(w);
    hi[idx] = h;
    lo[idx] = f2bf(w - bf2f(h));
}

// fused (w @ blockdiag(rel)) transposed+split: j = l*4 + dir*2 + kv
__global__ void prep_fused_k(const float* kw_q, const float* kw_a,
                             const float* vw_q, const float* vw_a,
                             const float* a_rel, const float* m_rel,
                             u16* __restrict__ hi, u16* __restrict__ lo) {
    int j = blockIdx.y;
    int l = j >> 2, dir = (j >> 1) & 1, kv = j & 1;
    const float* w = kv ? (dir ? vw_a : vw_q) : (dir ? kw_a : kw_q);
    w += l * 16384;
    const float* rel = (kv ? m_rel : a_rel) + (l * 2 + dir) * 2048;
    int idx = blockIdx.x * 256 + threadIdx.x;       // 16384
    int m = idx >> 7, k = idx & 127;
    int h = m >> 4, f = m & 15;
    float s = 0.f;
#pragma unroll
    for (int d = 0; d < 16; d++)
        s += w[k * 128 + h * 16 + d] * rel[(h * 16 + d) * 16 + f];
    u16 hh = f2bf(s);
    hi[j * 16384 + m * 128 + k] = hh;
    lo[j * 16384 + m * 128 + k] = f2bf(s - bf2f(hh));
}

__global__ void prep_fbias_k(const float* kb_q, const float* kb_a,
                             const float* vb_q, const float* vb_a,
                             const float* a_rel, const float* m_rel,
                             float* __restrict__ outB) {
    int idx = blockIdx.x * 256 + threadIdx.x;       // 1024
    if (idx >= 1024) return;
    int j = idx >> 7, m = idx & 127;
    int l = j >> 2, dir = (j >> 1) & 1, kv = j & 1;
    int h = m >> 4, f = m & 15;
    const float* b = kv ? (dir ? vb_a : vb_q) : (dir ? kb_a : kb_q);
    b += l * 128;
    const float* rel = (kv ? m_rel : a_rel) + (l * 2 + dir) * 2048;
    float s = 0.f;
#pragma unroll
    for (int d = 0; d < 16; d++)
        s += b[h * 16 + d] * rel[(h * 16 + d) * 16 + f];
    outB[idx] = s;
}

// ---------- CSR build ----------
__global__ void hist_k(const int* __restrict__ dst, int E, int* __restrict__ deg) {
    int i = blockIdx.x * 256 + threadIdx.x;
    if (i < E) atomicAdd(&deg[dst[i]], 1);
}
__global__ void scanA_k(const int* __restrict__ deg, int* __restrict__ incl,
                        int* __restrict__ bsum, int n) {
    __shared__ int s[256];
    int i = blockIdx.x * 256 + threadIdx.x;
    int v = (i < n) ? deg[i] : 0;
    s[threadIdx.x] = v;
    __syncthreads();
    for (int off = 1; off < 256; off <<= 1) {
        int t = (threadIdx.x >= off) ? s[threadIdx.x - off] : 0;
        __syncthreads();
        s[threadIdx.x] += t;
        __syncthreads();
    }
    if (i < n) incl[i] = s[threadIdx.x];
    if (threadIdx.x == 255) bsum[blockIdx.x] = s[255];
}
__global__ void scanB_k(int* __restrict__ bsum, int nb) {   // nb <= 256
    __shared__ int s[256];
    int v = (threadIdx.x < nb) ? bsum[threadIdx.x] : 0;
    s[threadIdx.x] = v;
    __syncthreads();
    for (int off = 1; off < 256; off <<= 1) {
        int t = (threadIdx.x >= off) ? s[threadIdx.x - off] : 0;
        __syncthreads();
        s[threadIdx.x] += t;
        __syncthreads();
    }
    if (threadIdx.x < nb) bsum[threadIdx.x] = s[threadIdx.x] - v;  // exclusive
}
__global__ void scanC_k(const int* __restrict__ incl, const int* __restrict__ deg,
                        const int* __restrict__ bsum, int* __restrict__ offs,
                        int* __restrict__ cursor, int n, int Etot) {
    int i = blockIdx.x * 256 + threadIdx.x;
    if (i < n) {
        int o = incl[i] - deg[i] + bsum[blockIdx.x];
        offs[i] = o;
        cursor[i] = o;
    }
    if (i == 0) offs[n] = Etot;
}
__global__ void scatter_k(const int* __restrict__ src, const int* __restrict__ dst, int E,
                          int* __restrict__ cursor, int* __restrict__ src_csr) {
    int e = blockIdx.x * 256 + threadIdx.x;
    if (e < E) {
        int p = atomicAdd(&cursor[dst[e]], 1);
        src_csr[p] = src[e];
    }
}

// ---------- fused edge phase: alpha + segment-softmax + weighted V + GELU ----------
// One 64-lane wave per destination node. Lanes = 8 edges (jj) x 8 heads (h) for
// the QK phase; = 64 channel-pairs for the V phase. Online softmax over chunks
// of 8 edges. msg[n][c] = gelu( sum_e softmax(alpha)_e * vt[src_e][c] )
__global__ __launch_bounds__(256) void edge_fused_k(
    const int* __restrict__ offs, const int* __restrict__ src_csr,
    const u16* __restrict__ kt, const u16* __restrict__ vt,
    const u16* __restrict__ qd, const float* __restrict__ pr,
    float* __restrict__ msg, int n) {
    int lane = threadIdx.x & 63;
    int node = blockIdx.x * 4 + (threadIdx.x >> 6);
    if (node >= n) return;
    int s0 = offs[node], s1 = offs[node + 1];
    int h = lane & 7, jj = lane >> 3;
    int hc = lane >> 3;                 // head of this lane's channel pair

    float accx = 0.f, accy = 0.f;
    float m = -INFINITY, den = 0.f;

    if (s0 < s1) {
        const u16* qrow = qd + (size_t)node * 128 + h * 16;
        uint4 q0 = *(const uint4*)qrow;
        uint4 q1 = *(const uint4*)(qrow + 8);
        float prh = pr[h] * 0.25f;      // SCALE = 1/sqrt(16)

        for (int base = s0; base < s1; base += 8) {
            int cnt = s1 - base; if (cnt > 8) cnt = 8;
            int j = base + jj;
            int src = src_csr[(j < s1) ? j : (s1 - 1)];
            const u16* krow = kt + (size_t)src * 128 + h * 16;
            uint4 k0 = *(const uint4*)krow;
            uint4 k1 = *(const uint4*)(krow + 8);
            float a = dotpair(k0.x, q0.x) + dotpair(k0.y, q0.y)
                    + dotpair(k0.z, q0.z) + dotpair(k0.w, q0.w)
                    + dotpair(k1.x, q1.x) + dotpair(k1.y, q1.y)
                    + dotpair(k1.z, q1.z) + dotpair(k1.w, q1.w);
            a = (jj < cnt) ? a * prh : -INFINITY;

            // per-head chunk max over jj lanes (lane bits 3..5)
            float cm = a;
            cm = fmaxf(cm, __shfl_xor(cm, 8));
            cm = fmaxf(cm, __shfl_xor(cm, 16));
            cm = fmaxf(cm, __shfl_xor(cm, 32));
            float mn = fmaxf(m, cm);
            float scale = __expf(m - mn);          // first chunk: exp(-inf)=0
            float p = __expf(a - mn);              // invalid lanes: 0
            float ps = p;
            ps += __shfl_xor(ps, 8);
            ps += __shfl_xor(ps, 16);
            ps += __shfl_xor(ps, 32);
            den = den * scale + ps;
            m = mn;

            float sc = __shfl(scale, hc);          // rescale for channel's head
            accx *= sc; accy *= sc;
#pragma unroll
            for (int t = 0; t < 8; t++) {
                if (t < cnt) {                      // wave-uniform branch
                    float w = __shfl(p, t * 8 + hc);
                    int s2 = __shfl(src, t * 8);
                    u32 v = *(const u32*)(vt + (size_t)s2 * 128 + lane * 2);
                    accx += w * bf2f((u16)(v & 0xffffu));
                    accy += w * bf2f((u16)(v >> 16));
                }
            }
        }
    }

    float dc = __shfl(den, hc);
    float inv = (dc > 0.f) ? (1.f / dc) : 0.f;
    float vx = accx * inv, vy = accy * inv;
    vx = 0.5f * vx * (1.f + erff(vx * 0.70710678118654752f));
    vy = 0.5f * vy * (1.f + erff(vy * 0.70710678118654752f));
    *(float2*)(msg + (size_t)node * 128 + lane * 2) = make_float2(vx, vy);
}

// ---------- register GEMM: Y[N][MOUT] = act(X[N][128] @ W + b) ----------
// X f32; W pre-transposed+split bf16 hi/lo [MOUT][128]; 3-MFMA split => ~f32 accuracy.
template <int MOUT, int ACT, bool SKIP, bool OUTBF16>
__global__ __launch_bounds__(256) void gemm_rr(
    const float* __restrict__ X, const u16* __restrict__ Whi, const u16* __restrict__ Wlo,
    const float* __restrict__ bias, const float* skipx, const float* gate,
    void* Y, int N) {
    int wave = threadIdx.x >> 6, lane = threadIdx.x & 63;
    int lr = lane & 15, kg = lane >> 4;
    int arow = blockIdx.x * 64 + wave * 16 + lr;

    float a[32];
#pragma unroll
    for (int ks = 0; ks < 4; ks++) {
        float4 v0 = make_float4(0.f, 0.f, 0.f, 0.f), v1 = v0;
        if (arow < N) {
            const float* p = X + (size_t)arow * 128 + ks * 32 + kg * 8;
            v0 = *(const float4*)p;
            v1 = *(const float4*)(p + 4);
        }
        a[ks * 8 + 0] = v0.x; a[ks * 8 + 1] = v0.y; a[ks * 8 + 2] = v0.z; a[ks * 8 + 3] = v0.w;
        a[ks * 8 + 4] = v1.x; a[ks * 8 + 5] = v1.y; a[ks * 8 + 6] = v1.z; a[ks * 8 + 7] = v1.w;
    }
    short8 ahi[4], alo[4];
#pragma unroll
    for (int ks = 0; ks < 4; ks++) {
#pragma unroll
        for (int j = 0; j < 8; j++) {
            float w = a[ks * 8 + j];
            u16 h = f2bf(w);
            ahi[ks][j] = (short)h;
            alo[ks][j] = (short)f2bf(w - bf2f(h));
        }
    }

    constexpr int NCT = MOUT / 16;
    f32x4 acc[NCT];
#pragma unroll
    for (int i = 0; i < NCT; i++) acc[i] = f32x4{0.f, 0.f, 0.f, 0.f};

#pragma unroll
    for (int ks = 0; ks < 4; ks++) {
#pragma unroll
        for (int ct = 0; ct < NCT; ct++) {
            size_t wof = (size_t)(ct * 16 + lr) * 128 + ks * 32 + kg * 8;
            short8 whi = *(const short8*)(Whi + wof);
            short8 wlo = *(const short8*)(Wlo + wof);
            acc[ct] = __builtin_amdgcn_mfma_f32_16x16x32_bf16(ahi[ks], whi, acc[ct], 0, 0, 0);
            acc[ct] = __builtin_amdgcn_mfma_f32_16x16x32_bf16(alo[ks], whi, acc[ct], 0, 0, 0);
            acc[ct] = __builtin_amdgcn_mfma_f32_16x16x32_bf16(ahi[ks], wlo, acc[ct], 0, 0, 0);
        }
    }

    float g = 1.f, gi = 0.f;
    if (SKIP) {
        float sk = gate[0];
        g = 1.f / (1.f + __expf(-sk));
        gi = 1.f - g;
    }
    int crow0 = blockIdx.x * 64 + wave * 16 + kg * 4;
#pragma unroll
    for (int ct = 0; ct < NCT; ct++) {
        int col = ct * 16 + lr;
        float bcol = bias[col];
#pragma unroll
        for (int r = 0; r < 4; r++) {
            int gr = crow0 + r;
            if (gr < N) {
                float v = acc[ct][r] + bcol;
                if (ACT == 1) v = fmaxf(v, 0.f);
                if (SKIP) v = g * v + gi * skipx[(size_t)gr * 128 + col];
                if (OUTBF16) ((u16*)Y)[(size_t)gr * MOUT + col] = f2bf(v);
                else         ((float*)Y)[(size_t)gr * MOUT + col] = v;
            }
        }
    }
}

// ---------- launch ----------
extern "C" void kernel_launch(void* const* d_in, const int* in_sizes, int n_in,
                              void* d_out, int out_size, void* d_ws, size_t ws_size,
                              hipStream_t stream) {
    const int NQ = in_sizes[0] / 128;
    const int NA = in_sizes[1] / 128;
    const int Eqa = in_sizes[29] / 2;
    const int Eaq = in_sizes[30] / 2;
    const int NM = (NQ > NA) ? NQ : NA;

    const float* x_q     = (const float*)d_in[0];
    const float* x_a     = (const float*)d_in[1];
    const float* lin0_wq = (const float*)d_in[2];
    const float* lin0_bq = (const float*)d_in[3];
    const float* lin0_wa = (const float*)d_in[4];
    const float* lin0_ba = (const float*)d_in[5];
    const float* kw_q = (const float*)d_in[6];
    const float* kb_q = (const float*)d_in[7];
    const float* qw_q = (const float*)d_in[8];
    const float* qb_q = (const float*)d_in[9];
    const float* vw_q = (const float*)d_in[10];
    const float* vb_q = (const float*)d_in[11];
    const float* aw_q = (const float*)d_in[12];
    const float* ab_q = (const float*)d_in[13];
    const float* kw_a = (const float*)d_in[14];
    const float* kb_a = (const float*)d_in[15];
    const float* qw_a = (const float*)d_in[16];
    const float* qb_a = (const float*)d_in[17];
    const float* vw_a = (const float*)d_in[18];
    const float* vb_a = (const float*)d_in[19];
    const float* aw_a = (const float*)d_in[20];
    const float* ab_a = (const float*)d_in[21];
    const float* skip_q = (const float*)d_in[22];
    const float* skip_a = (const float*)d_in[23];
    const float* a_rel = (const float*)d_in[24];
    const float* m_rel = (const float*)d_in[25];
    const float* p_rel = (const float*)d_in[26];
    const float* lin_w = (const float*)d_in[27];
    const float* lin_b = (const float*)d_in[28];
    const int* ei_qa = (const int*)d_in[29];
    const int* ei_aq = (const int*)d_in[30];

    // ---- workspace layout ----
    size_t off = 0;
    auto alloc = [&](size_t bytes) -> void* {
        void* p = (char*)d_ws + off;
        off += (bytes + 255) & ~(size_t)255;
        return p;
    };
    float* xq   = (float*)alloc((size_t)NQ * 128 * 4);
    float* xa   = (float*)alloc((size_t)NA * 128 * 4);
    float* msgq = (float*)alloc((size_t)NQ * 128 * 4);
    float* msga = (float*)alloc((size_t)NA * 128 * 4);
    u16* kt   = (u16*)alloc((size_t)NM * 128 * 2);
    u16* vt   = (u16*)alloc((size_t)NM * 128 * 2);
    u16* qd   = (u16*)alloc((size_t)NM * 128 * 2);
    int* offs_a = (int*)alloc((size_t)(NA + 1) * 4);
    int* offs_q = (int*)alloc((size_t)(NQ + 1) * 4);
    int* srcc_a = (int*)alloc((size_t)Eqa * 4);   // src ids in CSR order (dst=answer)
    int* srcc_q = (int*)alloc((size_t)Eaq * 4);   // src ids in CSR order (dst=question)
    int* deg    = (int*)alloc((size_t)NM * 4);
    int* cursor = (int*)alloc((size_t)NM * 4);
    int* incl   = (int*)alloc((size_t)NM * 4);
    int* bsum   = (int*)alloc(1024);
    u16* W_LIN0Q_h = (u16*)alloc(16384 * 2); u16* W_LIN0Q_l = (u16*)alloc(16384 * 2);
    u16* W_LIN0A_h = (u16*)alloc(16384 * 2); u16* W_LIN0A_l = (u16*)alloc(16384 * 2);
    u16* W_QQ_h = (u16*)alloc(2 * 16384 * 2); u16* W_QQ_l = (u16*)alloc(2 * 16384 * 2);
    u16* W_QA_h = (u16*)alloc(2 * 16384 * 2); u16* W_QA_l = (u16*)alloc(2 * 16384 * 2);
    u16* W_AQ_h = (u16*)alloc(2 * 16384 * 2); u16* W_AQ_l = (u16*)alloc(2 * 16384 * 2);
    u16* W_AA_h = (u16*)alloc(2 * 16384 * 2); u16* W_AA_l = (u16*)alloc(2 * 16384 * 2);
    u16* W_F_h  = (u16*)alloc(8 * 16384 * 2); u16* W_F_l  = (u16*)alloc(8 * 16384 * 2);
    u16* W_LIN_h = (u16*)alloc(8192 * 2);     u16* W_LIN_l = (u16*)alloc(8192 * 2);
    float* BF = (float*)alloc(8 * 128 * 4);
    (void)ws_size; (void)n_in; (void)out_size;

    dim3 B(256);
    auto T = [&](const float* src, u16* hi, u16* lo, int M) {
        prep_wt_k<<<dim3((M * 128 + 255) / 256), B, 0, stream>>>(src, hi, lo, M);
    };
    T(lin0_wq, W_LIN0Q_h, W_LIN0Q_l, 128);
    T(lin0_wa, W_LIN0A_h, W_LIN0A_l, 128);
    for (int l = 0; l < 2; l++) {
        T(qw_q + l * 16384, W_QQ_h + l * 16384, W_QQ_l + l * 16384, 128);
        T(qw_a + l * 16384, W_QA_h + l * 16384, W_QA_l + l * 16384, 128);
        T(aw_q + l * 16384, W_AQ_h + l * 16384, W_AQ_l + l * 16384, 128);
        T(aw_a + l * 16384, W_AA_h + l * 16384, W_AA_l + l * 16384, 128);
    }
    T(lin_w, W_LIN_h, W_LIN_l, 64);
    prep_fused_k<<<dim3(64, 8), B, 0, stream>>>(kw_q, kw_a, vw_q, vw_a, a_rel, m_rel, W_F_h, W_F_l);
    prep_fbias_k<<<dim3(4), B, 0, stream>>>(kb_q, kb_a, vb_q, vb_a, a_rel, m_rel, BF);

    // CSR build (keyed by dst = row 1 of ei); stores src ids in CSR order
    auto buildCSR = [&](const int* eibase, int Etot, int n, int* offs, int* src_csr) {
        const int* srcRow = eibase;
        const int* dstRow = eibase + Etot;
        int gE = (Etot + 255) / 256, gN = (n + 255) / 256;
        hipMemsetAsync(deg, 0, (size_t)n * 4, stream);
        hist_k<<<dim3(gE), B, 0, stream>>>(dstRow, Etot, deg);
        scanA_k<<<dim3(gN), B, 0, stream>>>(deg, incl, bsum, n);
        scanB_k<<<dim3(1), B, 0, stream>>>(bsum, gN);
        scanC_k<<<dim3(gN), B, 0, stream>>>(incl, deg, bsum, offs, cursor, n, Etot);
        scatter_k<<<dim3(gE), B, 0, stream>>>(srcRow, dstRow, Etot, cursor, src_csr);
    };
    buildCSR(ei_qa, Eqa, NA, offs_a, srcc_a);
    buildCSR(ei_aq, Eaq, NQ, offs_q, srcc_q);

    auto Glin0 = [&](const float* X, const u16* wh, const u16* wl, const float* b, float* Y, int N) {
        gemm_rr<128, 1, false, false><<<dim3((N + 63) / 64), B, 0, stream>>>(X, wh, wl, b, nullptr, nullptr, Y, N);
    };
    auto Gbf = [&](const float* X, const u16* wh, const u16* wl, const float* b, u16* Y, int N) {
        gemm_rr<128, 0, false, true><<<dim3((N + 63) / 64), B, 0, stream>>>(X, wh, wl, b, nullptr, nullptr, Y, N);
    };
    auto Gskip = [&](const float* X, const u16* wh, const u16* wl, const float* b,
                     const float* skipx, const float* gate, float* Y, int N) {
        gemm_rr<128, 0, true, false><<<dim3((N + 63) / 64), B, 0, stream>>>(X, wh, wl, b, skipx, gate, Y, N);
    };
    auto Gfin = [&](const float* X, float* Y, int N) {
        gemm_rr<64, 0, false, false><<<dim3((N + 63) / 64), B, 0, stream>>>(X, W_LIN_h, W_LIN_l, lin_b, nullptr, nullptr, Y, N);
    };
    auto EF = [&](const int* offs, const int* src_csr, const float* prp, float* msg, int n) {
        edge_fused_k<<<dim3((n + 3) / 4), B, 0, stream>>>(offs, src_csr, kt, vt, qd, prp, msg, n);
    };

    // input projections + relu
    Glin0(x_q, W_LIN0Q_h, W_LIN0Q_l, lin0_bq, xq, NQ);
    Glin0(x_a, W_LIN0A_h, W_LIN0A_l, lin0_ba, xa, NA);

    for (int l = 0; l < 2; l++) {
        // dir 0: question -> answer
        Gbf(xa, W_QA_h + l * 16384, W_QA_l + l * 16384, qb_a + l * 128, qd, NA);
        Gbf(xq, W_F_h + (l * 4 + 0) * 16384, W_F_l + (l * 4 + 0) * 16384, BF + (l * 4 + 0) * 128, kt, NQ);
        Gbf(xq, W_F_h + (l * 4 + 1) * 16384, W_F_l + (l * 4 + 1) * 16384, BF + (l * 4 + 1) * 128, vt, NQ);
        EF(offs_a, srcc_a, p_rel + (l * 2 + 0) * 8, msga, NA);
        // dir 1: answer -> question
        Gbf(xq, W_QQ_h + l * 16384, W_QQ_l + l * 16384, qb_q + l * 128, qd, NQ);
        Gbf(xa, W_F_h + (l * 4 + 2) * 16384, W_F_l + (l * 4 + 2) * 16384, BF + (l * 4 + 2) * 128, kt, NA);
        Gbf(xa, W_F_h + (l * 4 + 3) * 16384, W_F_l + (l * 4 + 3) * 16384, BF + (l * 4 + 3) * 128, vt, NA);
        EF(offs_q, srcc_q, p_rel + (l * 2 + 1) * 8, msgq, NQ);
        // output projections + gated skip (per-element read-then-write, same thread)
        Gskip(msgq, W_AQ_h + l * 16384, W_AQ_l + l * 16384, ab_q + l * 128, xq, skip_q + l, xq, NQ);
        Gskip(msga, W_AA_h + l * 16384, W_AA_l + l * 16384, ab_a + l * 128, xa, skip_a + l, xa, NA);
    }

    // final linear into d_out (rows [0,NQ) question, [NQ,NQ+NA) answer), f32 out
    Gfin(xq, (float*)d_out, NQ);
    Gfin(xa, (float*)d_out + (size_t)NQ * 64, NA);
}

// Round 4
// 1125.341 us; speedup vs baseline: 1.5267x; 1.0586x over previous
//
#include <hip/hip_runtime.h>
#include <hip/hip_bf16.h>
#include <math.h>

typedef __attribute__((ext_vector_type(8))) short short8;
typedef __attribute__((ext_vector_type(4))) float f32x4;
typedef unsigned short u16;
typedef unsigned int u32;

// ---------- helpers ----------
__device__ __forceinline__ float bf2f(u16 u) {
    union { u32 i; float f; } x; x.i = ((u32)u) << 16; return x.f;
}
__device__ __forceinline__ u16 f2bf(float f) {
    union { float f; u32 i; } u; u.f = f;
    u32 r = u.i + 0x7fffu + ((u.i >> 16) & 1u);   // RNE
    return (u16)(r >> 16);
}
__device__ __forceinline__ float dotpair(u32 a, u32 b) {
    union { u32 i; float f; } alo, ahi, blo, bhi;
    alo.i = a << 16; ahi.i = a & 0xffff0000u;
    blo.i = b << 16; bhi.i = b & 0xffff0000u;
    return alo.f * blo.f + ahi.f * bhi.f;
}

// ---------- batched weight prep ----------
struct TJob { const float* src; u16* hi; u16* lo; int M; };
struct TJobs { TJob j[11]; };

// out_hi/lo[m][128] = split(in[k][m]) for 11 matrices (blockIdx.y selects)
__global__ void prep_wt_all_k(TJobs jobs) {
    TJob t = jobs.j[blockIdx.y];
    int idx = blockIdx.x * 256 + threadIdx.x;
    if (idx >= t.M * 128) return;
    int m = idx >> 7, k = idx & 127;
    float w = t.src[k * t.M + m];
    u16 h = f2bf(w);
    t.hi[idx] = h;
    t.lo[idx] = f2bf(w - bf2f(h));
}

// fused (w @ blockdiag(rel)) transposed+split into WQ384 / WA256 slots
__global__ void prep_fused_k(const float* kw_q, const float* kw_a,
                             const float* vw_q, const float* vw_a,
                             const float* a_rel, const float* m_rel,
                             u16* WQ384h, u16* WQ384l, u16* WA256h, u16* WA256l) {
    int j = blockIdx.y;
    int l = j >> 2, dir = (j >> 1) & 1, kv = j & 1;
    const float* w = kv ? (dir ? vw_a : vw_q) : (dir ? kw_a : kw_q);
    w += l * 16384;
    const float* rel = (kv ? m_rel : a_rel) + (l * 2 + dir) * 2048;
    u16* dhi; u16* dlo;
    if (dir == 0) { dhi = WQ384h + (l * 384 + kv * 128) * 128; dlo = WQ384l + (l * 384 + kv * 128) * 128; }
    else          { dhi = WA256h + (l * 256 + kv * 128) * 128; dlo = WA256l + (l * 256 + kv * 128) * 128; }
    int idx = blockIdx.x * 256 + threadIdx.x;       // 16384
    int m = idx >> 7, k = idx & 127;
    int h = m >> 4, f = m & 15;
    float s = 0.f;
#pragma unroll
    for (int d = 0; d < 16; d++)
        s += w[k * 128 + h * 16 + d] * rel[(h * 16 + d) * 16 + f];
    u16 hh = f2bf(s);
    dhi[m * 128 + k] = hh;
    dlo[m * 128 + k] = f2bf(s - bf2f(hh));
}

// assemble BQ384 [2][384] and BA256 [2][256] (f32)
__global__ void prep_bias_k(const float* kb_q, const float* vb_q,
                            const float* kb_a, const float* vb_a,
                            const float* qb_q, const float* a_rel, const float* m_rel,
                            float* BQ384, float* BA256) {
    int idx = blockIdx.x * 256 + threadIdx.x;
    if (idx >= 1280) return;
    if (idx < 768) {
        int l = idx / 384, m = idx % 384;
        if (m < 256) {
            int kv = m >> 7, mc = m & 127, h = mc >> 4, f = mc & 15;
            const float* b = (kv ? vb_q : kb_q) + l * 128;
            const float* rel = (kv ? m_rel : a_rel) + (l * 2 + 0) * 2048;
            float s = 0.f;
#pragma unroll
            for (int d = 0; d < 16; d++) s += b[h * 16 + d] * rel[(h * 16 + d) * 16 + f];
            BQ384[l * 384 + m] = s;
        } else {
            BQ384[l * 384 + m] = qb_q[l * 128 + (m - 256)];
        }
    } else {
        int r = idx - 768; int l = r / 256, m = r % 256;
        int kv = m >> 7, mc = m & 127, h = mc >> 4, f = mc & 15;
        const float* b = (kv ? vb_a : kb_a) + l * 128;
        const float* rel = (kv ? m_rel : a_rel) + (l * 2 + 1) * 2048;
        float s = 0.f;
#pragma unroll
        for (int d = 0; d < 16; d++) s += b[h * 16 + d] * rel[(h * 16 + d) * 16 + f];
        BA256[l * 256 + m] = s;
    }
}

// ---------- batched CSR build (y = edge-set index) ----------
__global__ void hist2_k(const int* dA, int Ea, int* degA,
                        const int* dB, int Eb, int* degB) {
    int y = blockIdx.y;
    const int* dst = y ? dB : dA; int E = y ? Eb : Ea; int* deg = y ? degB : degA;
    int i = blockIdx.x * 256 + threadIdx.x;
    if (i < E) atomicAdd(&deg[dst[i]], 1);
}
__global__ void scanA2_k(const int* degA, int* inclA, int* bsumA, int nA,
                         const int* degB, int* inclB, int* bsumB, int nB) {
    int y = blockIdx.y;
    const int* deg = y ? degB : degA; int* incl = y ? inclB : inclA;
    int* bsum = y ? bsumB : bsumA; int n = y ? nB : nA;
    __shared__ int s[256];
    int i = blockIdx.x * 256 + threadIdx.x;
    int v = (i < n) ? deg[i] : 0;
    s[threadIdx.x] = v;
    __syncthreads();
    for (int off = 1; off < 256; off <<= 1) {
        int t = (threadIdx.x >= off) ? s[threadIdx.x - off] : 0;
        __syncthreads();
        s[threadIdx.x] += t;
        __syncthreads();
    }
    if (i < n) incl[i] = s[threadIdx.x];
    if (threadIdx.x == 255) bsum[blockIdx.x] = s[255];
}
__global__ void scanB2_k(int* bsumA, int nbA, int* bsumB, int nbB) {
    int* bsum = blockIdx.x ? bsumB : bsumA;
    int nb = blockIdx.x ? nbB : nbA;
    __shared__ int s[256];
    int v = (threadIdx.x < nb) ? bsum[threadIdx.x] : 0;
    s[threadIdx.x] = v;
    __syncthreads();
    for (int off = 1; off < 256; off <<= 1) {
        int t = (threadIdx.x >= off) ? s[threadIdx.x - off] : 0;
        __syncthreads();
        s[threadIdx.x] += t;
        __syncthreads();
    }
    if (threadIdx.x < nb) bsum[threadIdx.x] = s[threadIdx.x] - v;  // exclusive
}
__global__ void scanC2_k(const int* inclA, const int* degA, const int* bsumA,
                         int* offsA, int* curA, int nA, int Ea,
                         const int* inclB, const int* degB, const int* bsumB,
                         int* offsB, int* curB, int nB, int Eb) {
    int y = blockIdx.y;
    const int* incl = y ? inclB : inclA; const int* deg = y ? degB : degA;
    const int* bsum = y ? bsumB : bsumA;
    int* offs = y ? offsB : offsA; int* cur = y ? curB : curA;
    int n = y ? nB : nA; int E = y ? Eb : Ea;
    int i = blockIdx.x * 256 + threadIdx.x;
    if (i < n) {
        int o = incl[i] - deg[i] + bsum[blockIdx.x];
        offs[i] = o;
        cur[i] = o;
    }
    if (i == 0) offs[n] = E;
}
__global__ void scatter2_k(const int* eiA, int Ea, int* curA, int* srccA,
                           const int* eiB, int Eb, int* curB, int* srccB) {
    int y = blockIdx.y;
    const int* ei = y ? eiB : eiA; int E = y ? Eb : Ea;
    int* cur = y ? curB : curA; int* srcc = y ? srccB : srccA;
    int e = blockIdx.x * 256 + threadIdx.x;
    if (e < E) {
        int p = atomicAdd(&cur[ei[E + e]], 1);   // dst row
        srcc[p] = ei[e];                          // src id in CSR order
    }
}

// ---------- fused edge phase: alpha + segment-softmax + weighted V + GELU ----------
__global__ __launch_bounds__(256) void edge_fused_k(
    const int* __restrict__ offs, const int* __restrict__ src_csr,
    const u16* __restrict__ kt, const u16* __restrict__ vt,
    const u16* __restrict__ qd, const float* __restrict__ pr,
    float* __restrict__ msg, int n) {
    int lane = threadIdx.x & 63;
    int node = blockIdx.x * 4 + (threadIdx.x >> 6);
    if (node >= n) return;
    int s0 = offs[node], s1 = offs[node + 1];
    int h = lane & 7, jj = lane >> 3;
    int hc = lane >> 3;                 // head of this lane's channel pair

    float accx = 0.f, accy = 0.f;
    float m = -INFINITY, den = 0.f;

    if (s0 < s1) {
        const u16* qrow = qd + (size_t)node * 128 + h * 16;
        uint4 q0 = *(const uint4*)qrow;
        uint4 q1 = *(const uint4*)(qrow + 8);
        float prh = pr[h] * 0.25f;      // SCALE = 1/sqrt(16)

        for (int base = s0; base < s1; base += 8) {
            int cnt = s1 - base; if (cnt > 8) cnt = 8;
            int j = base + jj;
            int src = src_csr[(j < s1) ? j : (s1 - 1)];
            const u16* krow = kt + (size_t)src * 128 + h * 16;
            uint4 k0 = *(const uint4*)krow;
            uint4 k1 = *(const uint4*)(krow + 8);
            float a = dotpair(k0.x, q0.x) + dotpair(k0.y, q0.y)
                    + dotpair(k0.z, q0.z) + dotpair(k0.w, q0.w)
                    + dotpair(k1.x, q1.x) + dotpair(k1.y, q1.y)
                    + dotpair(k1.z, q1.z) + dotpair(k1.w, q1.w);
            a = (jj < cnt) ? a * prh : -INFINITY;

            float cm = a;
            cm = fmaxf(cm, __shfl_xor(cm, 8));
            cm = fmaxf(cm, __shfl_xor(cm, 16));
            cm = fmaxf(cm, __shfl_xor(cm, 32));
            float mn = fmaxf(m, cm);
            float scale = __expf(m - mn);
            float p = __expf(a - mn);
            float ps = p;
            ps += __shfl_xor(ps, 8);
            ps += __shfl_xor(ps, 16);
            ps += __shfl_xor(ps, 32);
            den = den * scale + ps;
            m = mn;

            float sc = __shfl(scale, hc);
            accx *= sc; accy *= sc;
#pragma unroll
            for (int t = 0; t < 8; t++) {
                if (t < cnt) {
                    float w = __shfl(p, t * 8 + hc);
                    int s2 = __shfl(src, t * 8);
                    u32 v = *(const u32*)(vt + (size_t)s2 * 128 + lane * 2);
                    accx += w * bf2f((u16)(v & 0xffffu));
                    accy += w * bf2f((u16)(v >> 16));
                }
            }
        }
    }

    float dc = __shfl(den, hc);
    float inv = (dc > 0.f) ? (1.f / dc) : 0.f;
    float vx = accx * inv, vy = accy * inv;
    vx = 0.5f * vx * (1.f + erff(vx * 0.70710678118654752f));
    vy = 0.5f * vy * (1.f + erff(vy * 0.70710678118654752f));
    *(float2*)(msg + (size_t)node * 128 + lane * 2) = make_float2(vx, vy);
}

// ---------- A-fragment load + bf16 hi/lo split (shared by GEMMs) ----------
__device__ __forceinline__ void load_a_frags(const float* X, int arow, int N,
                                             int kg, short8* ahi, short8* alo) {
#pragma unroll
    for (int ks = 0; ks < 4; ks++) {
        float4 v0 = make_float4(0.f, 0.f, 0.f, 0.f), v1 = v0;
        if (arow < N) {
            const float* p = X + (size_t)arow * 128 + ks * 32 + kg * 8;
            v0 = *(const float4*)p;
            v1 = *(const float4*)(p + 4);
        }
        float a8[8] = {v0.x, v0.y, v0.z, v0.w, v1.x, v1.y, v1.z, v1.w};
#pragma unroll
        for (int j = 0; j < 8; j++) {
            u16 h = f2bf(a8[j]);
            ahi[ks][j] = (short)h;
            alo[ks][j] = (short)f2bf(a8[j] - bf2f(h));
        }
    }
}

// ---------- multi-output GEMM: X[N,128] @ W[128, NB*128] -> NB bf16 [N,128] bufs ----------
template <int NB>
__global__ __launch_bounds__(256) void gemm_multi(
    const float* __restrict__ X, const u16* __restrict__ Whi, const u16* __restrict__ Wlo,
    const float* __restrict__ bias, u16* __restrict__ Y0, u16* __restrict__ Y1,
    u16* __restrict__ Y2, int N) {
    int wave = threadIdx.x >> 6, lane = threadIdx.x & 63;
    int lr = lane & 15, kg = lane >> 4;
    int arow = blockIdx.x * 64 + wave * 16 + lr;

    short8 ahi[4], alo[4];
    load_a_frags(X, arow, N, kg, ahi, alo);

    constexpr int NCT = NB * 8;
    f32x4 acc[NCT];
#pragma unroll
    for (int i = 0; i < NCT; i++) acc[i] = f32x4{0.f, 0.f, 0.f, 0.f};

#pragma unroll
    for (int ks = 0; ks < 4; ks++) {
#pragma unroll
        for (int ct = 0; ct < NCT; ct++) {
            size_t wof = (size_t)(ct * 16 + lr) * 128 + ks * 32 + kg * 8;
            short8 whi = *(const short8*)(Whi + wof);
            short8 wlo = *(const short8*)(Wlo + wof);
            acc[ct] = __builtin_amdgcn_mfma_f32_16x16x32_bf16(ahi[ks], whi, acc[ct], 0, 0, 0);
            acc[ct] = __builtin_amdgcn_mfma_f32_16x16x32_bf16(alo[ks], whi, acc[ct], 0, 0, 0);
            acc[ct] = __builtin_amdgcn_mfma_f32_16x16x32_bf16(ahi[ks], wlo, acc[ct], 0, 0, 0);
        }
    }

    int crow0 = blockIdx.x * 64 + wave * 16 + kg * 4;
#pragma unroll
    for (int ct = 0; ct < NCT; ct++) {
        int col = ct * 16 + lr;
        u16* Y = (ct < 8) ? Y0 : ((ct < 16) ? Y1 : Y2);
        int c = col & 127;
        float bcol = bias[col];
#pragma unroll
        for (int r = 0; r < 4; r++) {
            int gr = crow0 + r;
            if (gr < N) Y[(size_t)gr * 128 + c] = f2bf(acc[ct][r] + bcol);
        }
    }
}

// ---------- single-output GEMM (relu / bf16-out / skip / final-64) ----------
template <int MOUT, int ACT, bool SKIP, bool OUTBF16>
__global__ __launch_bounds__(256) void gemm_rr(
    const float* __restrict__ X, const u16* __restrict__ Whi, const u16* __restrict__ Wlo,
    const float* __restrict__ bias, const float* skipx, const float* gate,
    void* Y, int N) {
    int wave = threadIdx.x >> 6, lane = threadIdx.x & 63;
    int lr = lane & 15, kg = lane >> 4;
    int arow = blockIdx.x * 64 + wave * 16 + lr;

    short8 ahi[4], alo[4];
    load_a_frags(X, arow, N, kg, ahi, alo);

    constexpr int NCT = MOUT / 16;
    f32x4 acc[NCT];
#pragma unroll
    for (int i = 0; i < NCT; i++) acc[i] = f32x4{0.f, 0.f, 0.f, 0.f};

#pragma unroll
    for (int ks = 0; ks < 4; ks++) {
#pragma unroll
        for (int ct = 0; ct < NCT; ct++) {
            size_t wof = (size_t)(ct * 16 + lr) * 128 + ks * 32 + kg * 8;
            short8 whi = *(const short8*)(Whi + wof);
            short8 wlo = *(const short8*)(Wlo + wof);
            acc[ct] = __builtin_amdgcn_mfma_f32_16x16x32_bf16(ahi[ks], whi, acc[ct], 0, 0, 0);
            acc[ct] = __builtin_amdgcn_mfma_f32_16x16x32_bf16(alo[ks], whi, acc[ct], 0, 0, 0);
            acc[ct] = __builtin_amdgcn_mfma_f32_16x16x32_bf16(ahi[ks], wlo, acc[ct], 0, 0, 0);
        }
    }

    float g = 1.f, gi = 0.f;
    if (SKIP) {
        float sk = gate[0];
        g = 1.f / (1.f + __expf(-sk));
        gi = 1.f - g;
    }
    int crow0 = blockIdx.x * 64 + wave * 16 + kg * 4;
#pragma unroll
    for (int ct = 0; ct < NCT; ct++) {
        int col = ct * 16 + lr;
        float bcol = bias[col];
#pragma unroll
        for (int r = 0; r < 4; r++) {
            int gr = crow0 + r;
            if (gr < N) {
                float v = acc[ct][r] + bcol;
                if (ACT == 1) v = fmaxf(v, 0.f);
                if (SKIP) v = g * v + gi * skipx[(size_t)gr * 128 + col];
                if (OUTBF16) ((u16*)Y)[(size_t)gr * MOUT + col] = f2bf(v);
                else         ((float*)Y)[(size_t)gr * MOUT + col] = v;
            }
        }
    }
}

// ---------- launch ----------
extern "C" void kernel_launch(void* const* d_in, const int* in_sizes, int n_in,
                              void* d_out, int out_size, void* d_ws, size_t ws_size,
                              hipStream_t stream) {
    const int NQ = in_sizes[0] / 128;
    const int NA = in_sizes[1] / 128;
    const int Eqa = in_sizes[29] / 2;
    const int Eaq = in_sizes[30] / 2;
    const int NM = (NQ > NA) ? NQ : NA;
    const int EM = (Eqa > Eaq) ? Eqa : Eaq;

    const float* x_q     = (const float*)d_in[0];
    const float* x_a     = (const float*)d_in[1];
    const float* lin0_wq = (const float*)d_in[2];
    const float* lin0_bq = (const float*)d_in[3];
    const float* lin0_wa = (const float*)d_in[4];
    const float* lin0_ba = (const float*)d_in[5];
    const float* kw_q = (const float*)d_in[6];
    const float* qw_q = (const float*)d_in[8];
    const float* qb_q = (const float*)d_in[9];
    const float* vw_q = (const float*)d_in[10];
    const float* kb_q = (const float*)d_in[7];
    const float* vb_q = (const float*)d_in[11];
    const float* aw_q = (const float*)d_in[12];
    const float* ab_q = (const float*)d_in[13];
    const float* kw_a = (const float*)d_in[14];
    const float* kb_a = (const float*)d_in[15];
    const float* qw_a = (const float*)d_in[16];
    const float* qb_a = (const float*)d_in[17];
    const float* vw_a = (const float*)d_in[18];
    const float* vb_a = (const float*)d_in[19];
    const float* aw_a = (const float*)d_in[20];
    const float* ab_a = (const float*)d_in[21];
    const float* skip_q = (const float*)d_in[22];
    const float* skip_a = (const float*)d_in[23];
    const float* a_rel = (const float*)d_in[24];
    const float* m_rel = (const float*)d_in[25];
    const float* p_rel = (const float*)d_in[26];
    const float* lin_w = (const float*)d_in[27];
    const float* lin_b = (const float*)d_in[28];
    const int* ei_qa = (const int*)d_in[29];
    const int* ei_aq = (const int*)d_in[30];

    // ---- workspace layout ----
    size_t off = 0;
    auto alloc = [&](size_t bytes) -> void* {
        void* p = (char*)d_ws + off;
        off += (bytes + 255) & ~(size_t)255;
        return p;
    };
    float* xq   = (float*)alloc((size_t)NQ * 128 * 4);
    float* xa   = (float*)alloc((size_t)NA * 128 * 4);
    float* msgq = (float*)alloc((size_t)NQ * 128 * 4);
    float* msga = (float*)alloc((size_t)NA * 128 * 4);
    u16* kt  = (u16*)alloc((size_t)NM * 128 * 2);
    u16* vt  = (u16*)alloc((size_t)NM * 128 * 2);
    u16* qd  = (u16*)alloc((size_t)NM * 128 * 2);
    u16* qd2 = (u16*)alloc((size_t)NM * 128 * 2);
    int* offs_a = (int*)alloc((size_t)(NA + 1) * 4);
    int* offs_q = (int*)alloc((size_t)(NQ + 1) * 4);
    int* srcc_a = (int*)alloc((size_t)Eqa * 4);
    int* srcc_q = (int*)alloc((size_t)Eaq * 4);
    int* deg    = (int*)alloc((size_t)2 * NM * 4);   // [2][NM]
    int* cursor = (int*)alloc((size_t)2 * NM * 4);
    int* incl   = (int*)alloc((size_t)2 * NM * 4);
    int* bsum   = (int*)alloc(2048);                  // [2][256]
    u16* W_LIN0Q_h = (u16*)alloc(16384 * 2); u16* W_LIN0Q_l = (u16*)alloc(16384 * 2);
    u16* W_LIN0A_h = (u16*)alloc(16384 * 2); u16* W_LIN0A_l = (u16*)alloc(16384 * 2);
    u16* WQ384_h = (u16*)alloc(2 * 384 * 128 * 2); u16* WQ384_l = (u16*)alloc(2 * 384 * 128 * 2);
    u16* WA256_h = (u16*)alloc(2 * 256 * 128 * 2); u16* WA256_l = (u16*)alloc(2 * 256 * 128 * 2);
    u16* WA128_h = (u16*)alloc(2 * 16384 * 2);     u16* WA128_l = (u16*)alloc(2 * 16384 * 2);
    u16* W_AQ_h = (u16*)alloc(2 * 16384 * 2); u16* W_AQ_l = (u16*)alloc(2 * 16384 * 2);
    u16* W_AA_h = (u16*)alloc(2 * 16384 * 2); u16* W_AA_l = (u16*)alloc(2 * 16384 * 2);
    u16* W_LIN_h = (u16*)alloc(8192 * 2);     u16* W_LIN_l = (u16*)alloc(8192 * 2);
    float* BQ384 = (float*)alloc(2 * 384 * 4);
    float* BA256 = (float*)alloc(2 * 256 * 4);
    (void)ws_size; (void)n_in; (void)out_size; (void)EM;

    dim3 B(256);

    // weight prep: 3 dispatches
    TJobs tj;
    tj.j[0]  = {lin0_wq, W_LIN0Q_h, W_LIN0Q_l, 128};
    tj.j[1]  = {lin0_wa, W_LIN0A_h, W_LIN0A_l, 128};
    tj.j[2]  = {qw_q,          WQ384_h + (0 * 384 + 256) * 128, WQ384_l + (0 * 384 + 256) * 128, 128};
    tj.j[3]  = {qw_q + 16384,  WQ384_h + (1 * 384 + 256) * 128, WQ384_l + (1 * 384 + 256) * 128, 128};
    tj.j[4]  = {qw_a,          WA128_h,           WA128_l,           128};
    tj.j[5]  = {qw_a + 16384,  WA128_h + 16384,   WA128_l + 16384,   128};
    tj.j[6]  = {aw_q,          W_AQ_h,            W_AQ_l,            128};
    tj.j[7]  = {aw_q + 16384,  W_AQ_h + 16384,    W_AQ_l + 16384,    128};
    tj.j[8]  = {aw_a,          W_AA_h,            W_AA_l,            128};
    tj.j[9]  = {aw_a + 16384,  W_AA_h + 16384,    W_AA_l + 16384,    128};
    tj.j[10] = {lin_w,         W_LIN_h,           W_LIN_l,           64};
    prep_wt_all_k<<<dim3(64, 11), B, 0, stream>>>(tj);
    prep_fused_k<<<dim3(64, 8), B, 0, stream>>>(kw_q, kw_a, vw_q, vw_a, a_rel, m_rel,
                                                WQ384_h, WQ384_l, WA256_h, WA256_l);
    prep_bias_k<<<dim3(5), B, 0, stream>>>(kb_q, vb_q, kb_a, vb_a, qb_q, a_rel, m_rel, BQ384, BA256);

    // CSR build: 6 dispatches (set A: ei_qa keyed by answer; set B: ei_aq keyed by question)
    int* degA = deg;        int* degB = deg + NM;
    int* curA = cursor;     int* curB = cursor + NM;
    int* incA = incl;       int* incB = incl + NM;
    int* bsA  = bsum;       int* bsB  = bsum + 256;
    int gEm = ((EM) + 255) / 256, gNm = (NM + 255) / 256;
    int gNa = (NA + 255) / 256, gNq = (NQ + 255) / 256;
    hipMemsetAsync(deg, 0, (size_t)2 * NM * 4, stream);
    hist2_k<<<dim3(gEm, 2), B, 0, stream>>>(ei_qa + Eqa, Eqa, degA, ei_aq + Eaq, Eaq, degB);
    scanA2_k<<<dim3(gNm, 2), B, 0, stream>>>(degA, incA, bsA, NA, degB, incB, bsB, NQ);
    scanB2_k<<<dim3(2), B, 0, stream>>>(bsA, gNa, bsB, gNq);
    scanC2_k<<<dim3(gNm, 2), B, 0, stream>>>(incA, degA, bsA, offs_a, curA, NA, Eqa,
                                             incB, degB, bsB, offs_q, curB, NQ, Eaq);
    scatter2_k<<<dim3(gEm, 2), B, 0, stream>>>(ei_qa, Eqa, curA, srcc_a,
                                               ei_aq, Eaq, curB, srcc_q);

    auto Glin0 = [&](const float* X, const u16* wh, const u16* wl, const float* b, float* Y, int N) {
        gemm_rr<128, 1, false, false><<<dim3((N + 63) / 64), B, 0, stream>>>(X, wh, wl, b, nullptr, nullptr, Y, N);
    };
    auto Gbf = [&](const float* X, const u16* wh, const u16* wl, const float* b, u16* Y, int N) {
        gemm_rr<128, 0, false, true><<<dim3((N + 63) / 64), B, 0, stream>>>(X, wh, wl, b, nullptr, nullptr, Y, N);
    };
    auto Gskip = [&](const float* X, const u16* wh, const u16* wl, const float* b,
                     const float* skipx, const float* gate, float* Y, int N) {
        gemm_rr<128, 0, true, false><<<dim3((N + 63) / 64), B, 0, stream>>>(X, wh, wl, b, skipx, gate, Y, N);
    };
    auto EF = [&](const int* offs, const int* srcc, const u16* ktp, const u16* vtp,
                  const u16* qdp, const float* prp, float* msg, int n) {
        edge_fused_k<<<dim3((n + 3) / 4), B, 0, stream>>>(offs, srcc, ktp, vtp, qdp, prp, msg, n);
    };

    // input projections + relu
    Glin0(x_q, W_LIN0Q_h, W_LIN0Q_l, lin0_bq, xq, NQ);
    Glin0(x_a, W_LIN0A_h, W_LIN0A_l, lin0_ba, xa, NA);

    for (int l = 0; l < 2; l++) {
        // fromQ: kt0|vt0 (dir0 fused) and qdq (dir1 query), all from xq
        gemm_multi<3><<<dim3((NQ + 63) / 64), B, 0, stream>>>(
            xq, WQ384_h + l * 384 * 128, WQ384_l + l * 384 * 128, BQ384 + l * 384,
            kt, vt, qd2, NQ);
        // qda (dir0 query) from xa
        Gbf(xa, WA128_h + l * 16384, WA128_l + l * 16384, qb_a + l * 128, qd, NA);
        // dir0: question -> answer
        EF(offs_a, srcc_a, kt, vt, qd, p_rel + (l * 2 + 0) * 8, msga, NA);
        // fromA: kt1|vt1 (dir1 fused) from xa
        gemm_multi<2><<<dim3((NA + 63) / 64), B, 0, stream>>>(
            xa, WA256_h + l * 256 * 128, WA256_l + l * 256 * 128, BA256 + l * 256,
            kt, vt, nullptr, NA);
        // dir1: answer -> question
        EF(offs_q, srcc_q, kt, vt, qd2, p_rel + (l * 2 + 1) * 8, msgq, NQ);
        // output projections + gated skip
        Gskip(msgq, W_AQ_h + l * 16384, W_AQ_l + l * 16384, ab_q + l * 128, xq, skip_q + l, xq, NQ);
        Gskip(msga, W_AA_h + l * 16384, W_AA_l + l * 16384, ab_a + l * 128, xa, skip_a + l, xa, NA);
    }

    // final linear into d_out (rows [0,NQ) question, [NQ,NQ+NA) answer), f32 out
    gemm_rr<64, 0, false, false><<<dim3((NQ + 63) / 64), B, 0, stream>>>(
        xq, W_LIN_h, W_LIN_l, lin_b, nullptr, nullptr, (float*)d_out, NQ);
    gemm_rr<64, 0, false, false><<<dim3((NA + 63) / 64), B, 0, stream>>>(
        xa, W_LIN_h, W_LIN_l, lin_b, nullptr, nullptr, (float*)d_out + (size_t)NQ * 64, NA);
}

// Round 5
// 731.539 us; speedup vs baseline: 2.3485x; 1.5383x over previous
//
#include <hip/hip_runtime.h>
#include <hip/hip_bf16.h>
#include <math.h>

typedef __attribute__((ext_vector_type(8))) short short8;
typedef __attribute__((ext_vector_type(4))) float f32x4;
typedef unsigned short u16;
typedef unsigned int u32;

// ---------- helpers ----------
__device__ __forceinline__ float bf2f(u16 u) {
    union { u32 i; float f; } x; x.i = ((u32)u) << 16; return x.f;
}
__device__ __forceinline__ u16 f2bf(float f) {
    union { float f; u32 i; } u; u.f = f;
    u32 r = u.i + 0x7fffu + ((u.i >> 16) & 1u);   // RNE
    return (u16)(r >> 16);
}
__device__ __forceinline__ float dotpair(u32 a, u32 b) {
    union { u32 i; float f; } alo, ahi, blo, bhi;
    alo.i = a << 16; ahi.i = a & 0xffff0000u;
    blo.i = b << 16; bhi.i = b & 0xffff0000u;
    return alo.f * blo.f + ahi.f * bhi.f;
}
// swizzled W layout: fragment-major so a wave's ds_read_b128 is base+lane*16 (0 conflicts)
// m = output col within 128-chunk (or 64), k = input dim
__device__ __forceinline__ int swz_idx(int m, int k) {
    return ((((m >> 4) * 4 + (k >> 5)) * 4 + ((k >> 3) & 3)) * 16 + (m & 15)) * 8 + (k & 7);
}

// ---------- batched weight prep (writes swizzled hi/lo) ----------
struct TJob { const float* src; u16* hi; u16* lo; int M; };
struct TJobs { TJob j[11]; };

__global__ void prep_wt_all_k(TJobs jobs) {
    TJob t = jobs.j[blockIdx.y];
    int idx = blockIdx.x * 256 + threadIdx.x;
    if (idx >= t.M * 128) return;
    int m = idx >> 7, k = idx & 127;
    float w = t.src[k * t.M + m];
    u16 h = f2bf(w);
    int o = swz_idx(m, k);
    t.hi[o] = h;
    t.lo[o] = f2bf(w - bf2f(h));
}

// fused (w @ blockdiag(rel)) -> WQ[l][kv] / WA[l][kv] chunks (swizzled)
__global__ void prep_fused_k(const float* kw_q, const float* kw_a,
                             const float* vw_q, const float* vw_a,
                             const float* a_rel, const float* m_rel,
                             u16* WQh, u16* WQl, u16* WAh, u16* WAl) {
    int j = blockIdx.y;
    int l = j >> 2, dir = (j >> 1) & 1, kv = j & 1;
    const float* w = kv ? (dir ? vw_a : vw_q) : (dir ? kw_a : kw_q);
    w += l * 16384;
    const float* rel = (kv ? m_rel : a_rel) + (l * 2 + dir) * 2048;
    u16* dhi = (dir ? WAh : WQh) + (l * 3 + kv) * 16384;
    u16* dlo = (dir ? WAl : WQl) + (l * 3 + kv) * 16384;
    int idx = blockIdx.x * 256 + threadIdx.x;       // 16384
    int m = idx >> 7, k = idx & 127;
    int h = m >> 4, f = m & 15;
    float s = 0.f;
#pragma unroll
    for (int d = 0; d < 16; d++)
        s += w[k * 128 + h * 16 + d] * rel[(h * 16 + d) * 16 + f];
    u16 hh = f2bf(s);
    int o = swz_idx(m, k);
    dhi[o] = hh;
    dlo[o] = f2bf(s - bf2f(hh));
}

// BQ[2][384], BA[2][384] (f32): [fused kb | fused vb | qb]
__global__ void prep_bias_k(const float* kb_q, const float* vb_q, const float* qb_q,
                            const float* kb_a, const float* vb_a, const float* qb_a,
                            const float* a_rel, const float* m_rel,
                            float* BQ, float* BA) {
    int idx = blockIdx.x * 256 + threadIdx.x;
    if (idx >= 1536) return;
    int side = idx / 768, r = idx % 768;
    int l = r / 384, m = r % 384;
    float* dst = side ? BA : BQ;
    if (m >= 256) {
        const float* qb = side ? qb_a : qb_q;
        dst[l * 384 + m] = qb[l * 128 + (m - 256)];
        return;
    }
    int kv = m >> 7, mc = m & 127, h = mc >> 4, f = mc & 15;
    const float* b = side ? (kv ? vb_a : kb_a) : (kv ? vb_q : kb_q);
    b += l * 128;
    const float* rel = (kv ? m_rel : a_rel) + (l * 2 + side) * 2048;
    float s = 0.f;
#pragma unroll
    for (int d = 0; d < 16; d++) s += b[h * 16 + d] * rel[(h * 16 + d) * 16 + f];
    dst[l * 384 + m] = s;
}

// ---------- batched CSR build (y = edge-set index) ----------
__global__ void hist2_k(const int* dA, int Ea, int* degA,
                        const int* dB, int Eb, int* degB) {
    int y = blockIdx.y;
    const int* dst = y ? dB : dA; int E = y ? Eb : Ea; int* deg = y ? degB : degA;
    int i = blockIdx.x * 256 + threadIdx.x;
    if (i < E) atomicAdd(&deg[dst[i]], 1);
}
__global__ void scanA2_k(const int* degA, int* inclA, int* bsumA, int nA,
                         const int* degB, int* inclB, int* bsumB, int nB) {
    int y = blockIdx.y;
    const int* deg = y ? degB : degA; int* incl = y ? inclB : inclA;
    int* bsum = y ? bsumB : bsumA; int n = y ? nB : nA;
    __shared__ int s[256];
    int i = blockIdx.x * 256 + threadIdx.x;
    int v = (i < n) ? deg[i] : 0;
    s[threadIdx.x] = v;
    __syncthreads();
    for (int off = 1; off < 256; off <<= 1) {
        int t = (threadIdx.x >= off) ? s[threadIdx.x - off] : 0;
        __syncthreads();
        s[threadIdx.x] += t;
        __syncthreads();
    }
    if (i < n) incl[i] = s[threadIdx.x];
    if (threadIdx.x == 255) bsum[blockIdx.x] = s[255];
}
__global__ void scanB2_k(int* bsumA, int nbA, int* bsumB, int nbB) {
    int* bsum = blockIdx.x ? bsumB : bsumA;
    int nb = blockIdx.x ? nbB : nbA;
    __shared__ int s[256];
    int v = (threadIdx.x < nb) ? bsum[threadIdx.x] : 0;
    s[threadIdx.x] = v;
    __syncthreads();
    for (int off = 1; off < 256; off <<= 1) {
        int t = (threadIdx.x >= off) ? s[threadIdx.x - off] : 0;
        __syncthreads();
        s[threadIdx.x] += t;
        __syncthreads();
    }
    if (threadIdx.x < nb) bsum[threadIdx.x] = s[threadIdx.x] - v;  // exclusive
}
__global__ void scanC2_k(const int* inclA, const int* degA, const int* bsumA,
                         int* offsA, int* curA, int nA, int Ea,
                         const int* inclB, const int* degB, const int* bsumB,
                         int* offsB, int* curB, int nB, int Eb) {
    int y = blockIdx.y;
    const int* incl = y ? inclB : inclA; const int* deg = y ? degB : degA;
    const int* bsum = y ? bsumB : bsumA;
    int* offs = y ? offsB : offsA; int* cur = y ? curB : curA;
    int n = y ? nB : nA; int E = y ? Eb : Ea;
    int i = blockIdx.x * 256 + threadIdx.x;
    if (i < n) {
        int o = incl[i] - deg[i] + bsum[blockIdx.x];
        offs[i] = o;
        cur[i] = o;
    }
    if (i == 0) offs[n] = E;
}
__global__ void scatter2_k(const int* eiA, int Ea, int* curA, int* srccA,
                           const int* eiB, int Eb, int* curB, int* srccB) {
    int y = blockIdx.y;
    const int* ei = y ? eiB : eiA; int E = y ? Eb : Ea;
    int* cur = y ? curB : curA; int* srcc = y ? srccB : srccA;
    int e = blockIdx.x * 256 + threadIdx.x;
    if (e < E) {
        int p = atomicAdd(&cur[ei[E + e]], 1);   // dst row
        srcc[p] = ei[e];                          // src id in CSR order
    }
}

// ---------- fused edge phase: alpha + segment-softmax + weighted V + GELU ----------
__global__ __launch_bounds__(256) void edge_fused_k(
    const int* __restrict__ offs, const int* __restrict__ src_csr,
    const u16* __restrict__ kt, const u16* __restrict__ vt,
    const u16* __restrict__ qd, const float* __restrict__ pr,
    float* __restrict__ msg, int n) {
    int lane = threadIdx.x & 63;
    int node = blockIdx.x * 4 + (threadIdx.x >> 6);
    if (node >= n) return;
    int s0 = offs[node], s1 = offs[node + 1];
    int h = lane & 7, jj = lane >> 3;
    int hc = lane >> 3;                 // head of this lane's channel pair

    float accx = 0.f, accy = 0.f;
    float m = -INFINITY, den = 0.f;

    if (s0 < s1) {
        const u16* qrow = qd + (size_t)node * 128 + h * 16;
        uint4 q0 = *(const uint4*)qrow;
        uint4 q1 = *(const uint4*)(qrow + 8);
        float prh = pr[h] * 0.25f;      // SCALE = 1/sqrt(16)

        for (int base = s0; base < s1; base += 8) {
            int cnt = s1 - base; if (cnt > 8) cnt = 8;
            int j = base + jj;
            int src = src_csr[(j < s1) ? j : (s1 - 1)];
            const u16* krow = kt + (size_t)src * 128 + h * 16;
            uint4 k0 = *(const uint4*)krow;
            uint4 k1 = *(const uint4*)(krow + 8);
            float a = dotpair(k0.x, q0.x) + dotpair(k0.y, q0.y)
                    + dotpair(k0.z, q0.z) + dotpair(k0.w, q0.w)
                    + dotpair(k1.x, q1.x) + dotpair(k1.y, q1.y)
                    + dotpair(k1.z, q1.z) + dotpair(k1.w, q1.w);
            a = (jj < cnt) ? a * prh : -INFINITY;

            float cm = a;
            cm = fmaxf(cm, __shfl_xor(cm, 8));
            cm = fmaxf(cm, __shfl_xor(cm, 16));
            cm = fmaxf(cm, __shfl_xor(cm, 32));
            float mn = fmaxf(m, cm);
            float scale = __expf(m - mn);
            float p = __expf(a - mn);
            float ps = p;
            ps += __shfl_xor(ps, 8);
            ps += __shfl_xor(ps, 16);
            ps += __shfl_xor(ps, 32);
            den = den * scale + ps;
            m = mn;

            float sc = __shfl(scale, hc);
            accx *= sc; accy *= sc;
#pragma unroll
            for (int t = 0; t < 8; t++) {
                if (t < cnt) {
                    float w = __shfl(p, t * 8 + hc);
                    int s2 = __shfl(src, t * 8);
                    u32 v = *(const u32*)(vt + (size_t)s2 * 128 + lane * 2);
                    accx += w * bf2f((u16)(v & 0xffffu));
                    accy += w * bf2f((u16)(v >> 16));
                }
            }
        }
    }

    float dc = __shfl(den, hc);
    float inv = (dc > 0.f) ? (1.f / dc) : 0.f;
    float vx = accx * inv, vy = accy * inv;
    vx = 0.5f * vx * (1.f + erff(vx * 0.70710678118654752f));
    vy = 0.5f * vy * (1.f + erff(vy * 0.70710678118654752f));
    *(float2*)(msg + (size_t)node * 128 + lane * 2) = make_float2(vx, vy);
}

// ---------- LDS-staged GEMM ----------
// W (swizzled hi/lo, one 128-col (or 64) chunk per blockIdx.y) staged in LDS once;
// grid-stride over 64-row tiles, no barriers in the loop (LDS read-only).
// 3-MFMA bf16 split => ~f32 accuracy.
template <int MOUT, int ACT, bool SKIP, bool OUTBF16>
__global__ __launch_bounds__(256) void gemm_lds(
    const float* __restrict__ X, const u16* __restrict__ Wh, const u16* __restrict__ Wl,
    const float* __restrict__ bias, const float* __restrict__ skipx,
    const float* __restrict__ gate,
    void* Y0, void* Y1, void* Y2, int N) {
    constexpr int CH = MOUT * 128;          // u16 per matrix chunk
    __shared__ u16 Ws[2 * CH];              // hi | lo  (64KB for MOUT=128)
    int tid = threadIdx.x;
    int y = blockIdx.y;
    {
        const u16* wh = Wh + (size_t)y * CH;
        const u16* wl = Wl + (size_t)y * CH;
        constexpr int NV = CH / 8;          // uint4 count per matrix
#pragma unroll
        for (int i0 = 0; i0 < NV; i0 += 256) {
            int i = i0 + tid;
            *(uint4*)&Ws[i * 8]      = *(const uint4*)(wh + i * 8);
            *(uint4*)&Ws[CH + i * 8] = *(const uint4*)(wl + i * 8);
        }
    }
    __syncthreads();

    int wave = tid >> 6, lane = tid & 63;
    int lr = lane & 15, kg = lane >> 4;
    const int lb = kg * 128 + lr * 8;       // u16 lane base within fragment group
    constexpr int NCT = MOUT / 16;

    float g = 1.f, gi = 0.f;
    if (SKIP) {
        float sk = gate[0];
        g = 1.f / (1.f + __expf(-sk));
        gi = 1.f - g;
    }
    void* Yp = (y == 0) ? Y0 : ((y == 1) ? Y1 : Y2);

    int ntiles = (N + 63) >> 6;
    for (int tile = blockIdx.x; tile < ntiles; tile += gridDim.x) {
        int arow = tile * 64 + wave * 16 + lr;
        // A fragments (f32 global, hi/lo split)
        short8 ahi[4], alo[4];
#pragma unroll
        for (int ks = 0; ks < 4; ks++) {
            float4 v0 = make_float4(0.f, 0.f, 0.f, 0.f), v1 = v0;
            if (arow < N) {
                const float* p = X + (size_t)arow * 128 + ks * 32 + kg * 8;
                v0 = *(const float4*)p;
                v1 = *(const float4*)(p + 4);
            }
            float a8[8] = {v0.x, v0.y, v0.z, v0.w, v1.x, v1.y, v1.z, v1.w};
#pragma unroll
            for (int j = 0; j < 8; j++) {
                u16 h = f2bf(a8[j]);
                ahi[ks][j] = (short)h;
                alo[ks][j] = (short)f2bf(a8[j] - bf2f(h));
            }
        }

        f32x4 acc[NCT];
#pragma unroll
        for (int i = 0; i < NCT; i++) acc[i] = f32x4{0.f, 0.f, 0.f, 0.f};

#pragma unroll
        for (int ks = 0; ks < 4; ks++) {
#pragma unroll
            for (int ct = 0; ct < NCT; ct++) {
                int fo = lb + (ct * 4 + ks) * 512;
                short8 whi = *(const short8*)&Ws[fo];
                short8 wlo = *(const short8*)&Ws[CH + fo];
                acc[ct] = __builtin_amdgcn_mfma_f32_16x16x32_bf16(ahi[ks], whi, acc[ct], 0, 0, 0);
                acc[ct] = __builtin_amdgcn_mfma_f32_16x16x32_bf16(alo[ks], whi, acc[ct], 0, 0, 0);
                acc[ct] = __builtin_amdgcn_mfma_f32_16x16x32_bf16(ahi[ks], wlo, acc[ct], 0, 0, 0);
            }
        }

        int crow0 = tile * 64 + wave * 16 + kg * 4;
#pragma unroll
        for (int ct = 0; ct < NCT; ct++) {
            int col = ct * 16 + lr;
            float bcol = bias[y * 128 + col];
#pragma unroll
            for (int r = 0; r < 4; r++) {
                int gr = crow0 + r;
                if (gr < N) {
                    float v = acc[ct][r] + bcol;
                    if (ACT == 1) v = fmaxf(v, 0.f);
                    if (SKIP) v = g * v + gi * skipx[(size_t)gr * 128 + col];
                    if (OUTBF16) ((u16*)Yp)[(size_t)gr * MOUT + col] = f2bf(v);
                    else         ((float*)Yp)[(size_t)gr * MOUT + col] = v;
                }
            }
        }
    }
}

// ---------- launch ----------
extern "C" void kernel_launch(void* const* d_in, const int* in_sizes, int n_in,
                              void* d_out, int out_size, void* d_ws, size_t ws_size,
                              hipStream_t stream) {
    const int NQ = in_sizes[0] / 128;
    const int NA = in_sizes[1] / 128;
    const int Eqa = in_sizes[29] / 2;
    const int Eaq = in_sizes[30] / 2;
    const int NM = (NQ > NA) ? NQ : NA;
    const int EM = (Eqa > Eaq) ? Eqa : Eaq;

    const float* x_q     = (const float*)d_in[0];
    const float* x_a     = (const float*)d_in[1];
    const float* lin0_wq = (const float*)d_in[2];
    const float* lin0_bq = (const float*)d_in[3];
    const float* lin0_wa = (const float*)d_in[4];
    const float* lin0_ba = (const float*)d_in[5];
    const float* kw_q = (const float*)d_in[6];
    const float* kb_q = (const float*)d_in[7];
    const float* qw_q = (const float*)d_in[8];
    const float* qb_q = (const float*)d_in[9];
    const float* vw_q = (const float*)d_in[10];
    const float* vb_q = (const float*)d_in[11];
    const float* aw_q = (const float*)d_in[12];
    const float* ab_q = (const float*)d_in[13];
    const float* kw_a = (const float*)d_in[14];
    const float* kb_a = (const float*)d_in[15];
    const float* qw_a = (const float*)d_in[16];
    const float* qb_a = (const float*)d_in[17];
    const float* vw_a = (const float*)d_in[18];
    const float* vb_a = (const float*)d_in[19];
    const float* aw_a = (const float*)d_in[20];
    const float* ab_a = (const float*)d_in[21];
    const float* skip_q = (const float*)d_in[22];
    const float* skip_a = (const float*)d_in[23];
    const float* a_rel = (const float*)d_in[24];
    const float* m_rel = (const float*)d_in[25];
    const float* p_rel = (const float*)d_in[26];
    const float* lin_w = (const float*)d_in[27];
    const float* lin_b = (const float*)d_in[28];
    const int* ei_qa = (const int*)d_in[29];
    const int* ei_aq = (const int*)d_in[30];

    // ---- workspace layout ----
    size_t off = 0;
    auto alloc = [&](size_t bytes) -> void* {
        void* p = (char*)d_ws + off;
        off += (bytes + 255) & ~(size_t)255;
        return p;
    };
    float* xq   = (float*)alloc((size_t)NQ * 128 * 4);   // xq,xa contiguous: final GEMM
    float* xa   = (float*)alloc((size_t)NA * 128 * 4);   // runs over [xq|xa] as one X
    float* msgq = (float*)alloc((size_t)NQ * 128 * 4);
    float* msga = (float*)alloc((size_t)NA * 128 * 4);
    u16* kt0 = (u16*)alloc((size_t)NM * 128 * 2);
    u16* vt0 = (u16*)alloc((size_t)NM * 128 * 2);
    u16* qdq = (u16*)alloc((size_t)NM * 128 * 2);
    u16* kt1 = (u16*)alloc((size_t)NM * 128 * 2);
    u16* vt1 = (u16*)alloc((size_t)NM * 128 * 2);
    u16* qda = (u16*)alloc((size_t)NM * 128 * 2);
    int* offs_a = (int*)alloc((size_t)(NA + 1) * 4);
    int* offs_q = (int*)alloc((size_t)(NQ + 1) * 4);
    int* srcc_a = (int*)alloc((size_t)Eqa * 4);
    int* srcc_q = (int*)alloc((size_t)Eaq * 4);
    int* deg    = (int*)alloc((size_t)2 * NM * 4);
    int* cursor = (int*)alloc((size_t)2 * NM * 4);
    int* incl   = (int*)alloc((size_t)2 * NM * 4);
    int* bsum   = (int*)alloc(2048);
    u16* W_LIN0Q_h = (u16*)alloc(16384 * 2); u16* W_LIN0Q_l = (u16*)alloc(16384 * 2);
    u16* W_LIN0A_h = (u16*)alloc(16384 * 2); u16* W_LIN0A_l = (u16*)alloc(16384 * 2);
    u16* WQ_h = (u16*)alloc(2 * 3 * 16384 * 2); u16* WQ_l = (u16*)alloc(2 * 3 * 16384 * 2);
    u16* WA_h = (u16*)alloc(2 * 3 * 16384 * 2); u16* WA_l = (u16*)alloc(2 * 3 * 16384 * 2);
    u16* W_AQ_h = (u16*)alloc(2 * 16384 * 2); u16* W_AQ_l = (u16*)alloc(2 * 16384 * 2);
    u16* W_AA_h = (u16*)alloc(2 * 16384 * 2); u16* W_AA_l = (u16*)alloc(2 * 16384 * 2);
    u16* W_LIN_h = (u16*)alloc(8192 * 2);     u16* W_LIN_l = (u16*)alloc(8192 * 2);
    float* BQ = (float*)alloc(2 * 384 * 4);
    float* BA = (float*)alloc(2 * 384 * 4);
    (void)ws_size; (void)n_in; (void)out_size; (void)EM;

    dim3 B(256);

    // weight prep: 3 dispatches (all write swizzled layout)
    TJobs tj;
    tj.j[0]  = {lin0_wq, W_LIN0Q_h, W_LIN0Q_l, 128};
    tj.j[1]  = {lin0_wa, W_LIN0A_h, W_LIN0A_l, 128};
    tj.j[2]  = {qw_q,          WQ_h + (0 * 3 + 2) * 16384, WQ_l + (0 * 3 + 2) * 16384, 128};
    tj.j[3]  = {qw_q + 16384,  WQ_h + (1 * 3 + 2) * 16384, WQ_l + (1 * 3 + 2) * 16384, 128};
    tj.j[4]  = {qw_a,          WA_h + (0 * 3 + 2) * 16384, WA_l + (0 * 3 + 2) * 16384, 128};
    tj.j[5]  = {qw_a + 16384,  WA_h + (1 * 3 + 2) * 16384, WA_l + (1 * 3 + 2) * 16384, 128};
    tj.j[6]  = {aw_q,          W_AQ_h,            W_AQ_l,            128};
    tj.j[7]  = {aw_q + 16384,  W_AQ_h + 16384,    W_AQ_l + 16384,    128};
    tj.j[8]  = {aw_a,          W_AA_h,            W_AA_l,            128};
    tj.j[9]  = {aw_a + 16384,  W_AA_h + 16384,    W_AA_l + 16384,    128};
    tj.j[10] = {lin_w,         W_LIN_h,           W_LIN_l,           64};
    prep_wt_all_k<<<dim3(64, 11), B, 0, stream>>>(tj);
    prep_fused_k<<<dim3(64, 8), B, 0, stream>>>(kw_q, kw_a, vw_q, vw_a, a_rel, m_rel,
                                                WQ_h, WQ_l, WA_h, WA_l);
    prep_bias_k<<<dim3(6), B, 0, stream>>>(kb_q, vb_q, qb_q, kb_a, vb_a, qb_a,
                                           a_rel, m_rel, BQ, BA);

    // CSR build: 6 dispatches
    int* degA = deg;        int* degB = deg + NM;
    int* curA = cursor;     int* curB = cursor + NM;
    int* incA = incl;       int* incB = incl + NM;
    int* bsA  = bsum;       int* bsB  = bsum + 256;
    int gEm = (EM + 255) / 256, gNm = (NM + 255) / 256;
    int gNa = (NA + 255) / 256, gNq = (NQ + 255) / 256;
    hipMemsetAsync(deg, 0, (size_t)2 * NM * 4, stream);
    hist2_k<<<dim3(gEm, 2), B, 0, stream>>>(ei_qa + Eqa, Eqa, degA, ei_aq + Eaq, Eaq, degB);
    scanA2_k<<<dim3(gNm, 2), B, 0, stream>>>(degA, incA, bsA, NA, degB, incB, bsB, NQ);
    scanB2_k<<<dim3(2), B, 0, stream>>>(bsA, gNa, bsB, gNq);
    scanC2_k<<<dim3(gNm, 2), B, 0, stream>>>(incA, degA, bsA, offs_a, curA, NA, Eqa,
                                             incB, degB, bsB, offs_q, curB, NQ, Eaq);
    scatter2_k<<<dim3(gEm, 2), B, 0, stream>>>(ei_qa, Eqa, curA, srcc_a,
                                               ei_aq, Eaq, curB, srcc_q);

    auto gx = [&](int N) { int t = (N + 63) / 64; return t < 512 ? t : 512; };

    // input projections + relu (f32 out)
    gemm_lds<128, 1, false, false><<<dim3(gx(NQ), 1), B, 0, stream>>>(
        x_q, W_LIN0Q_h, W_LIN0Q_l, lin0_bq, nullptr, nullptr, xq, nullptr, nullptr, NQ);
    gemm_lds<128, 1, false, false><<<dim3(gx(NA), 1), B, 0, stream>>>(
        x_a, W_LIN0A_h, W_LIN0A_l, lin0_ba, nullptr, nullptr, xa, nullptr, nullptr, NA);

    for (int l = 0; l < 2; l++) {
        // xq -> [kt0 | vt0 | qdq]  (3 chunks, bf16 out)
        gemm_lds<128, 0, false, true><<<dim3(gx(NQ), 3), B, 0, stream>>>(
            xq, WQ_h + l * 3 * 16384, WQ_l + l * 3 * 16384, BQ + l * 384,
            nullptr, nullptr, kt0, vt0, qdq, NQ);
        // xa -> [kt1 | vt1 | qda]
        gemm_lds<128, 0, false, true><<<dim3(gx(NA), 3), B, 0, stream>>>(
            xa, WA_h + l * 3 * 16384, WA_l + l * 3 * 16384, BA + l * 384,
            nullptr, nullptr, kt1, vt1, qda, NA);
        // dir0: question -> answer
        edge_fused_k<<<dim3((NA + 3) / 4), B, 0, stream>>>(
            offs_a, srcc_a, kt0, vt0, qda, p_rel + (l * 2 + 0) * 8, msga, NA);
        // dir1: answer -> question
        edge_fused_k<<<dim3((NQ + 3) / 4), B, 0, stream>>>(
            offs_q, srcc_q, kt1, vt1, qdq, p_rel + (l * 2 + 1) * 8, msgq, NQ);
        // output projections + gated skip (in-place per-element read-then-write)
        gemm_lds<128, 0, true, false><<<dim3(gx(NQ), 1), B, 0, stream>>>(
            msgq, W_AQ_h + l * 16384, W_AQ_l + l * 16384, ab_q + l * 128,
            xq, skip_q + l, xq, nullptr, nullptr, NQ);
        gemm_lds<128, 0, true, false><<<dim3(gx(NA), 1), B, 0, stream>>>(
            msga, W_AA_h + l * 16384, W_AA_l + l * 16384, ab_a + l * 128,
            xa, skip_a + l, xa, nullptr, nullptr, NA);
    }

    // final linear over contiguous [xq|xa] rows -> d_out (f32)
    gemm_lds<64, 0, false, false><<<dim3(gx(NQ + NA), 1), B, 0, stream>>>(
        xq, W_LIN_h, W_LIN_l, lin_b, nullptr, nullptr, (float*)d_out, nullptr, nullptr, NQ + NA);
}

// Round 6
// 697.290 us; speedup vs baseline: 2.4639x; 1.0491x over previous
//
#include <hip/hip_runtime.h>
#include <hip/hip_bf16.h>
#include <math.h>

typedef __attribute__((ext_vector_type(8))) short short8;
typedef __attribute__((ext_vector_type(4))) float f32x4;
typedef unsigned short u16;
typedef unsigned int u32;

// ---------- helpers ----------
__device__ __forceinline__ float bf2f(u16 u) {
    union { u32 i; float f; } x; x.i = ((u32)u) << 16; return x.f;
}
__device__ __forceinline__ u16 f2bf(float f) {
    union { float f; u32 i; } u; u.f = f;
    u32 r = u.i + 0x7fffu + ((u.i >> 16) & 1u);   // RNE
    return (u16)(r >> 16);
}
__device__ __forceinline__ float dotpair(u32 a, u32 b) {
    union { u32 i; float f; } alo, ahi, blo, bhi;
    alo.i = a << 16; ahi.i = a & 0xffff0000u;
    blo.i = b << 16; bhi.i = b & 0xffff0000u;
    return alo.f * blo.f + ahi.f * bhi.f;
}
// swizzled W layout: fragment-major; lane reads frag at base+(ctg*4+ks)*512+kg*128+lr*8
__device__ __forceinline__ int swz_idx(int m, int k) {
    return ((((m >> 4) * 4 + (k >> 5)) * 4 + ((k >> 3) & 3)) * 16 + (m & 15)) * 8 + (k & 7);
}

// ---------- batched weight prep (writes swizzled hi/lo) ----------
struct TJob { const float* src; u16* hi; u16* lo; int M; };
struct TJobs { TJob j[11]; };

__global__ void prep_wt_all_k(TJobs jobs) {
    TJob t = jobs.j[blockIdx.y];
    int idx = blockIdx.x * 256 + threadIdx.x;
    if (idx >= t.M * 128) return;
    int m = idx >> 7, k = idx & 127;
    float w = t.src[k * t.M + m];
    u16 h = f2bf(w);
    int o = swz_idx(m, k);
    t.hi[o] = h;
    t.lo[o] = f2bf(w - bf2f(h));
}

// fused (w @ blockdiag(rel)) -> WQ[l][kv] / WA[l][kv] chunks (swizzled)
__global__ void prep_fused_k(const float* kw_q, const float* kw_a,
                             const float* vw_q, const float* vw_a,
                             const float* a_rel, const float* m_rel,
                             u16* WQh, u16* WQl, u16* WAh, u16* WAl) {
    int j = blockIdx.y;
    int l = j >> 2, dir = (j >> 1) & 1, kv = j & 1;
    const float* w = kv ? (dir ? vw_a : vw_q) : (dir ? kw_a : kw_q);
    w += l * 16384;
    const float* rel = (kv ? m_rel : a_rel) + (l * 2 + dir) * 2048;
    u16* dhi = (dir ? WAh : WQh) + (l * 3 + kv) * 16384;
    u16* dlo = (dir ? WAl : WQl) + (l * 3 + kv) * 16384;
    int idx = blockIdx.x * 256 + threadIdx.x;       // 16384
    int m = idx >> 7, k = idx & 127;
    int h = m >> 4, f = m & 15;
    float s = 0.f;
#pragma unroll
    for (int d = 0; d < 16; d++)
        s += w[k * 128 + h * 16 + d] * rel[(h * 16 + d) * 16 + f];
    u16 hh = f2bf(s);
    int o = swz_idx(m, k);
    dhi[o] = hh;
    dlo[o] = f2bf(s - bf2f(hh));
}

// BQ[2][384], BA[2][384] (f32): [fused kb | fused vb | qb]
__global__ void prep_bias_k(const float* kb_q, const float* vb_q, const float* qb_q,
                            const float* kb_a, const float* vb_a, const float* qb_a,
                            const float* a_rel, const float* m_rel,
                            float* BQ, float* BA) {
    int idx = blockIdx.x * 256 + threadIdx.x;
    if (idx >= 1536) return;
    int side = idx / 768, r = idx % 768;
    int l = r / 384, m = r % 384;
    float* dst = side ? BA : BQ;
    if (m >= 256) {
        const float* qb = side ? qb_a : qb_q;
        dst[l * 384 + m] = qb[l * 128 + (m - 256)];
        return;
    }
    int kv = m >> 7, mc = m & 127, h = mc >> 4, f = mc & 15;
    const float* b = side ? (kv ? vb_a : kb_a) : (kv ? vb_q : kb_q);
    b += l * 128;
    const float* rel = (kv ? m_rel : a_rel) + (l * 2 + side) * 2048;
    float s = 0.f;
#pragma unroll
    for (int d = 0; d < 16; d++) s += b[h * 16 + d] * rel[(h * 16 + d) * 16 + f];
    dst[l * 384 + m] = s;
}

// ---------- batched CSR build (y = edge-set index) ----------
__global__ void hist2_k(const int* dA, int Ea, int* degA,
                        const int* dB, int Eb, int* degB) {
    int y = blockIdx.y;
    const int* dst = y ? dB : dA; int E = y ? Eb : Ea; int* deg = y ? degB : degA;
    int i = blockIdx.x * 256 + threadIdx.x;
    if (i < E) atomicAdd(&deg[dst[i]], 1);
}
__global__ void scanA2_k(const int* degA, int* inclA, int* bsumA, int nA,
                         const int* degB, int* inclB, int* bsumB, int nB) {
    int y = blockIdx.y;
    const int* deg = y ? degB : degA; int* incl = y ? inclB : inclA;
    int* bsum = y ? bsumB : bsumA; int n = y ? nB : nA;
    __shared__ int s[256];
    int i = blockIdx.x * 256 + threadIdx.x;
    int v = (i < n) ? deg[i] : 0;
    s[threadIdx.x] = v;
    __syncthreads();
    for (int off = 1; off < 256; off <<= 1) {
        int t = (threadIdx.x >= off) ? s[threadIdx.x - off] : 0;
        __syncthreads();
        s[threadIdx.x] += t;
        __syncthreads();
    }
    if (i < n) incl[i] = s[threadIdx.x];
    if (threadIdx.x == 255) bsum[blockIdx.x] = s[255];
}
__global__ void scanB2_k(int* bsumA, int nbA, int* bsumB, int nbB) {
    int* bsum = blockIdx.x ? bsumB : bsumA;
    int nb = blockIdx.x ? nbB : nbA;
    __shared__ int s[256];
    int v = (threadIdx.x < nb) ? bsum[threadIdx.x] : 0;
    s[threadIdx.x] = v;
    __syncthreads();
    for (int off = 1; off < 256; off <<= 1) {
        int t = (threadIdx.x >= off) ? s[threadIdx.x - off] : 0;
        __syncthreads();
        s[threadIdx.x] += t;
        __syncthreads();
    }
    if (threadIdx.x < nb) bsum[threadIdx.x] = s[threadIdx.x] - v;  // exclusive
}
__global__ void scanC2_k(const int* inclA, const int* degA, const int* bsumA,
                         int* offsA, int* curA, int nA, int Ea,
                         const int* inclB, const int* degB, const int* bsumB,
                         int* offsB, int* curB, int nB, int Eb) {
    int y = blockIdx.y;
    const int* incl = y ? inclB : inclA; const int* deg = y ? degB : degA;
    const int* bsum = y ? bsumB : bsumA;
    int* offs = y ? offsB : offsA; int* cur = y ? curB : curA;
    int n = y ? nB : nA; int E = y ? Eb : Ea;
    int i = blockIdx.x * 256 + threadIdx.x;
    if (i < n) {
        int o = incl[i] - deg[i] + bsum[blockIdx.x];
        offs[i] = o;
        cur[i] = o;
    }
    if (i == 0) offs[n] = E;
}
__global__ void scatter2_k(const int* eiA, int Ea, int* curA, int* srccA,
                           const int* eiB, int Eb, int* curB, int* srccB) {
    int y = blockIdx.y;
    const int* ei = y ? eiB : eiA; int E = y ? Eb : Ea;
    int* cur = y ? curB : curA; int* srcc = y ? srccB : srccA;
    int e = blockIdx.x * 256 + threadIdx.x;
    if (e < E) {
        int p = atomicAdd(&cur[ei[E + e]], 1);   // dst row
        srcc[p] = ei[e];                          // src id in CSR order
    }
}

// ---------- fused edge phase: alpha + segment-softmax + weighted V + GELU ----------
// output: split bf16 planes (hi/lo)
__global__ __launch_bounds__(256) void edge_fused_k(
    const int* __restrict__ offs, const int* __restrict__ src_csr,
    const u16* __restrict__ kt, const u16* __restrict__ vt,
    const u16* __restrict__ qd, const float* __restrict__ pr,
    u16* __restrict__ mhi, u16* __restrict__ mlo, int n) {
    int lane = threadIdx.x & 63;
    int node = blockIdx.x * 4 + (threadIdx.x >> 6);
    if (node >= n) return;
    int s0 = offs[node], s1 = offs[node + 1];
    int h = lane & 7, jj = lane >> 3;
    int hc = lane >> 3;                 // head of this lane's channel pair

    float accx = 0.f, accy = 0.f;
    float m = -INFINITY, den = 0.f;

    if (s0 < s1) {
        const u16* qrow = qd + (size_t)node * 128 + h * 16;
        uint4 q0 = *(const uint4*)qrow;
        uint4 q1 = *(const uint4*)(qrow + 8);
        float prh = pr[h] * 0.25f;      // SCALE = 1/sqrt(16)

        int jf = s0 + jj;
        int src_next = src_csr[(jf < s1) ? jf : (s1 - 1)];
        for (int base = s0; base < s1; base += 8) {
            int cnt = s1 - base; if (cnt > 8) cnt = 8;
            int src = src_next;
            if (base + 8 < s1) {                    // prefetch next chunk's src ids
                int jn = base + 8 + jj;
                src_next = src_csr[(jn < s1) ? jn : (s1 - 1)];
            }
            const u16* krow = kt + (size_t)src * 128 + h * 16;
            uint4 k0 = *(const uint4*)krow;
            uint4 k1 = *(const uint4*)(krow + 8);
            float a = dotpair(k0.x, q0.x) + dotpair(k0.y, q0.y)
                    + dotpair(k0.z, q0.z) + dotpair(k0.w, q0.w)
                    + dotpair(k1.x, q1.x) + dotpair(k1.y, q1.y)
                    + dotpair(k1.z, q1.z) + dotpair(k1.w, q1.w);
            a = (jj < cnt) ? a * prh : -INFINITY;

            float cm = a;
            cm = fmaxf(cm, __shfl_xor(cm, 8));
            cm = fmaxf(cm, __shfl_xor(cm, 16));
            cm = fmaxf(cm, __shfl_xor(cm, 32));
            float mn = fmaxf(m, cm);
            float scale = __expf(m - mn);
            float p = __expf(a - mn);
            float ps = p;
            ps += __shfl_xor(ps, 8);
            ps += __shfl_xor(ps, 16);
            ps += __shfl_xor(ps, 32);
            den = den * scale + ps;
            m = mn;

            float sc = __shfl(scale, hc);
            accx *= sc; accy *= sc;
#pragma unroll
            for (int t = 0; t < 8; t++) {
                if (t < cnt) {
                    float w = __shfl(p, t * 8 + hc);
                    int s2 = __shfl(src, t * 8);
                    u32 v = *(const u32*)(vt + (size_t)s2 * 128 + lane * 2);
                    accx += w * bf2f((u16)(v & 0xffffu));
                    accy += w * bf2f((u16)(v >> 16));
                }
            }
        }
    }

    float dc = __shfl(den, hc);
    float inv = (dc > 0.f) ? (1.f / dc) : 0.f;
    float vx = accx * inv, vy = accy * inv;
    vx = 0.5f * vx * (1.f + erff(vx * 0.70710678118654752f));
    vy = 0.5f * vy * (1.f + erff(vy * 0.70710678118654752f));
    u16 hx = f2bf(vx), hy = f2bf(vy);
    u16 lx = f2bf(vx - bf2f(hx)), ly = f2bf(vy - bf2f(hy));
    size_t ob = (size_t)node * 128 + lane * 2;
    *(u32*)(mhi + ob) = (u32)hx | ((u32)hy << 16);
    *(u32*)(mlo + ob) = (u32)lx | ((u32)ly << 16);
}

// ---------- register-W GEMM ----------
// Each wave owns a 32-col W slice in VGPRs (loaded once, coalesced, pre-swizzled).
// A = split bf16 planes. 32 rows/tile (2x16 subtiles), grid-stride, no LDS/barriers.
// OUTMODE: 0=f32, 1=bf16 chunk (Y0/Y1/Y2 by blockIdx.y), 2=split planes (Y0=hi, Ylo)
template <int MOUT, int ACT, bool SKIP, int OUTMODE>
__global__ __launch_bounds__(256, 4) void gemm_regw(
    const u16* __restrict__ Xhi, const u16* __restrict__ Xlo,
    const u16* __restrict__ Wh, const u16* __restrict__ Wl,
    const float* __restrict__ bias,
    const u16* __restrict__ skhi, const u16* __restrict__ sklo,
    const float* __restrict__ gate,
    void* Y0, void* Y1, void* Y2, void* Ylo, int N) {
    constexpr int NCTW = MOUT / 64;          // col-fragments per wave (4 waves span MOUT)
    constexpr int CH = MOUT * 128;
    int tid = threadIdx.x;
    int wave = tid >> 6, lane = tid & 63;
    int lr = lane & 15, kg = lane >> 4;
    int y = blockIdx.y;

    short8 wh[NCTW][4], wl[NCTW][4];
    {
        const u16* wbh = Wh + (size_t)y * CH;
        const u16* wbl = Wl + (size_t)y * CH;
#pragma unroll
        for (int ct = 0; ct < NCTW; ct++)
#pragma unroll
            for (int ks = 0; ks < 4; ks++) {
                int o = ((wave * NCTW + ct) * 4 + ks) * 512 + kg * 128 + lr * 8;
                wh[ct][ks] = *(const short8*)(wbh + o);
                wl[ct][ks] = *(const short8*)(wbl + o);
            }
    }

    float g = 1.f, gi = 0.f;
    if (SKIP) {
        float sk = gate[0];
        g = 1.f / (1.f + __expf(-sk));
        gi = 1.f - g;
    }

    int ntiles = (N + 31) >> 5;
    for (int t = blockIdx.x; t < ntiles; t += gridDim.x) {
        short8 ahi[2][4], alo[2][4];
#pragma unroll
        for (int s = 0; s < 2; s++) {
            int arow = t * 32 + s * 16 + lr;
            if (arow >= N) arow = N - 1;          // clamp: pollutes only unstored C rows
            const u16* ph = Xhi + (size_t)arow * 128 + kg * 8;
            const u16* pl = Xlo + (size_t)arow * 128 + kg * 8;
#pragma unroll
            for (int ks = 0; ks < 4; ks++) {
                ahi[s][ks] = *(const short8*)(ph + ks * 32);
                alo[s][ks] = *(const short8*)(pl + ks * 32);
            }
        }

        f32x4 acc[2][NCTW];
#pragma unroll
        for (int s = 0; s < 2; s++)
#pragma unroll
            for (int i = 0; i < NCTW; i++) acc[s][i] = f32x4{0.f, 0.f, 0.f, 0.f};

#pragma unroll
        for (int ks = 0; ks < 4; ks++)
#pragma unroll
            for (int s = 0; s < 2; s++)
#pragma unroll
                for (int ct = 0; ct < NCTW; ct++) {
                    acc[s][ct] = __builtin_amdgcn_mfma_f32_16x16x32_bf16(ahi[s][ks], wh[ct][ks], acc[s][ct], 0, 0, 0);
                    acc[s][ct] = __builtin_amdgcn_mfma_f32_16x16x32_bf16(alo[s][ks], wh[ct][ks], acc[s][ct], 0, 0, 0);
                    acc[s][ct] = __builtin_amdgcn_mfma_f32_16x16x32_bf16(ahi[s][ks], wl[ct][ks], acc[s][ct], 0, 0, 0);
                }

#pragma unroll
        for (int s = 0; s < 2; s++) {
            int crow0 = t * 32 + s * 16 + kg * 4;
#pragma unroll
            for (int ct = 0; ct < NCTW; ct++) {
                int col = (wave * NCTW + ct) * 16 + lr;
                float bcol = bias[y * MOUT + col];
#pragma unroll
                for (int r = 0; r < 4; r++) {
                    int gr = crow0 + r;
                    if (gr < N) {
                        float v = acc[s][ct][r] + bcol;
                        if (ACT == 1) v = fmaxf(v, 0.f);
                        if (SKIP) {
                            size_t si = (size_t)gr * 128 + col;
                            v = g * v + gi * (bf2f(skhi[si]) + bf2f(sklo[si]));
                        }
                        if (OUTMODE == 1) {
                            u16* Yp = (u16*)((y == 0) ? Y0 : ((y == 1) ? Y1 : Y2));
                            Yp[(size_t)gr * 128 + col] = f2bf(v);
                        } else if (OUTMODE == 2) {
                            u16 hv = f2bf(v);
                            ((u16*)Y0)[(size_t)gr * 128 + col] = hv;
                            ((u16*)Ylo)[(size_t)gr * 128 + col] = f2bf(v - bf2f(hv));
                        } else {
                            ((float*)Y0)[(size_t)gr * MOUT + col] = v;
                        }
                    }
                }
            }
        }
    }
}

// f32-A variant (for the input projection); MOUT=128, split-plane output, ACT=relu
__global__ __launch_bounds__(256, 3) void gemm_regw_f32(
    const float* __restrict__ X,
    const u16* __restrict__ Wh, const u16* __restrict__ Wl,
    const float* __restrict__ bias,
    u16* __restrict__ Yhi, u16* __restrict__ Ylo, int N) {
    int tid = threadIdx.x;
    int wave = tid >> 6, lane = tid & 63;
    int lr = lane & 15, kg = lane >> 4;

    short8 wh[2][4], wl[2][4];
#pragma unroll
    for (int ct = 0; ct < 2; ct++)
#pragma unroll
        for (int ks = 0; ks < 4; ks++) {
            int o = ((wave * 2 + ct) * 4 + ks) * 512 + kg * 128 + lr * 8;
            wh[ct][ks] = *(const short8*)(Wh + o);
            wl[ct][ks] = *(const short8*)(Wl + o);
        }

    int ntiles = (N + 31) >> 5;
    for (int t = blockIdx.x; t < ntiles; t += gridDim.x) {
        short8 ahi[2][4], alo[2][4];
#pragma unroll
        for (int s = 0; s < 2; s++) {
            int arow = t * 32 + s * 16 + lr;
            if (arow >= N) arow = N - 1;
            const float* p = X + (size_t)arow * 128 + kg * 8;
#pragma unroll
            for (int ks = 0; ks < 4; ks++) {
                float4 v0 = *(const float4*)(p + ks * 32);
                float4 v1 = *(const float4*)(p + ks * 32 + 4);
                float a8[8] = {v0.x, v0.y, v0.z, v0.w, v1.x, v1.y, v1.z, v1.w};
#pragma unroll
                for (int j = 0; j < 8; j++) {
                    u16 h = f2bf(a8[j]);
                    ahi[s][ks][j] = (short)h;
                    alo[s][ks][j] = (short)f2bf(a8[j] - bf2f(h));
                }
            }
        }

        f32x4 acc[2][2];
#pragma unroll
        for (int s = 0; s < 2; s++)
#pragma unroll
            for (int i = 0; i < 2; i++) acc[s][i] = f32x4{0.f, 0.f, 0.f, 0.f};

#pragma unroll
        for (int ks = 0; ks < 4; ks++)
#pragma unroll
            for (int s = 0; s < 2; s++)
#pragma unroll
                for (int ct = 0; ct < 2; ct++) {
                    acc[s][ct] = __builtin_amdgcn_mfma_f32_16x16x32_bf16(ahi[s][ks], wh[ct][ks], acc[s][ct], 0, 0, 0);
                    acc[s][ct] = __builtin_amdgcn_mfma_f32_16x16x32_bf16(alo[s][ks], wh[ct][ks], acc[s][ct], 0, 0, 0);
                    acc[s][ct] = __builtin_amdgcn_mfma_f32_16x16x32_bf16(ahi[s][ks], wl[ct][ks], acc[s][ct], 0, 0, 0);
                }

#pragma unroll
        for (int s = 0; s < 2; s++) {
            int crow0 = t * 32 + s * 16 + kg * 4;
#pragma unroll
            for (int ct = 0; ct < 2; ct++) {
                int col = (wave * 2 + ct) * 16 + lr;
                float bcol = bias[col];
#pragma unroll
                for (int r = 0; r < 4; r++) {
                    int gr = crow0 + r;
                    if (gr < N) {
                        float v = fmaxf(acc[s][ct][r] + bcol, 0.f);   // relu
                        u16 hv = f2bf(v);
                        Yhi[(size_t)gr * 128 + col] = hv;
                        Ylo[(size_t)gr * 128 + col] = f2bf(v - bf2f(hv));
                    }
                }
            }
        }
    }
}

// ---------- launch ----------
extern "C" void kernel_launch(void* const* d_in, const int* in_sizes, int n_in,
                              void* d_out, int out_size, void* d_ws, size_t ws_size,
                              hipStream_t stream) {
    const int NQ = in_sizes[0] / 128;
    const int NA = in_sizes[1] / 128;
    const int Eqa = in_sizes[29] / 2;
    const int Eaq = in_sizes[30] / 2;
    const int NM = (NQ > NA) ? NQ : NA;
    const int EM = (Eqa > Eaq) ? Eqa : Eaq;

    const float* x_q     = (const float*)d_in[0];
    const float* x_a     = (const float*)d_in[1];
    const float* lin0_wq = (const float*)d_in[2];
    const float* lin0_bq = (const float*)d_in[3];
    const float* lin0_wa = (const float*)d_in[4];
    const float* lin0_ba = (const float*)d_in[5];
    const float* kw_q = (const float*)d_in[6];
    const float* kb_q = (const float*)d_in[7];
    const float* qw_q = (const float*)d_in[8];
    const float* qb_q = (const float*)d_in[9];
    const float* vw_q = (const float*)d_in[10];
    const float* vb_q = (const float*)d_in[11];
    const float* aw_q = (const float*)d_in[12];
    const float* ab_q = (const float*)d_in[13];
    const float* kw_a = (const float*)d_in[14];
    const float* kb_a = (const float*)d_in[15];
    const float* qw_a = (const float*)d_in[16];
    const float* qb_a = (const float*)d_in[17];
    const float* vw_a = (const float*)d_in[18];
    const float* vb_a = (const float*)d_in[19];
    const float* aw_a = (const float*)d_in[20];
    const float* ab_a = (const float*)d_in[21];
    const float* skip_q = (const float*)d_in[22];
    const float* skip_a = (const float*)d_in[23];
    const float* a_rel = (const float*)d_in[24];
    const float* m_rel = (const float*)d_in[25];
    const float* p_rel = (const float*)d_in[26];
    const float* lin_w = (const float*)d_in[27];
    const float* lin_b = (const float*)d_in[28];
    const int* ei_qa = (const int*)d_in[29];
    const int* ei_aq = (const int*)d_in[30];

    // ---- workspace ----
    size_t off = 0;
    auto alloc = [&](size_t bytes) -> void* {
        void* p = (char*)d_ws + off;
        off += (bytes + 255) & ~(size_t)255;
        return p;
    };
    u16* xhi = (u16*)alloc((size_t)(NQ + NA) * 128 * 2);   // rows [0,NQ)=q, [NQ,..)=a
    u16* xlo = (u16*)alloc((size_t)(NQ + NA) * 128 * 2);
    u16* xq_hi = xhi;            u16* xq_lo = xlo;
    u16* xa_hi = xhi + (size_t)NQ * 128;
    u16* xa_lo = xlo + (size_t)NQ * 128;
    u16* mq_hi = (u16*)alloc((size_t)NQ * 128 * 2);
    u16* mq_lo = (u16*)alloc((size_t)NQ * 128 * 2);
    u16* ma_hi = (u16*)alloc((size_t)NA * 128 * 2);
    u16* ma_lo = (u16*)alloc((size_t)NA * 128 * 2);
    u16* kt0 = (u16*)alloc((size_t)NM * 128 * 2);
    u16* vt0 = (u16*)alloc((size_t)NM * 128 * 2);
    u16* qdq = (u16*)alloc((size_t)NM * 128 * 2);
    u16* kt1 = (u16*)alloc((size_t)NM * 128 * 2);
    u16* vt1 = (u16*)alloc((size_t)NM * 128 * 2);
    u16* qda = (u16*)alloc((size_t)NM * 128 * 2);
    int* offs_a = (int*)alloc((size_t)(NA + 1) * 4);
    int* offs_q = (int*)alloc((size_t)(NQ + 1) * 4);
    int* srcc_a = (int*)alloc((size_t)Eqa * 4);
    int* srcc_q = (int*)alloc((size_t)Eaq * 4);
    int* deg    = (int*)alloc((size_t)2 * NM * 4);
    int* cursor = (int*)alloc((size_t)2 * NM * 4);
    int* incl   = (int*)alloc((size_t)2 * NM * 4);
    int* bsum   = (int*)alloc(2048);
    u16* W_LIN0Q_h = (u16*)alloc(16384 * 2); u16* W_LIN0Q_l = (u16*)alloc(16384 * 2);
    u16* W_LIN0A_h = (u16*)alloc(16384 * 2); u16* W_LIN0A_l = (u16*)alloc(16384 * 2);
    u16* WQ_h = (u16*)alloc(2 * 3 * 16384 * 2); u16* WQ_l = (u16*)alloc(2 * 3 * 16384 * 2);
    u16* WA_h = (u16*)alloc(2 * 3 * 16384 * 2); u16* WA_l = (u16*)alloc(2 * 3 * 16384 * 2);
    u16* W_AQ_h = (u16*)alloc(2 * 16384 * 2); u16* W_AQ_l = (u16*)alloc(2 * 16384 * 2);
    u16* W_AA_h = (u16*)alloc(2 * 16384 * 2); u16* W_AA_l = (u16*)alloc(2 * 16384 * 2);
    u16* W_LIN_h = (u16*)alloc(8192 * 2);     u16* W_LIN_l = (u16*)alloc(8192 * 2);
    float* BQ = (float*)alloc(2 * 384 * 4);
    float* BA = (float*)alloc(2 * 384 * 4);
    (void)ws_size; (void)n_in; (void)out_size; (void)EM;

    dim3 B(256);

    // weight prep: 3 dispatches (swizzled)
    TJobs tj;
    tj.j[0]  = {lin0_wq, W_LIN0Q_h, W_LIN0Q_l, 128};
    tj.j[1]  = {lin0_wa, W_LIN0A_h, W_LIN0A_l, 128};
    tj.j[2]  = {qw_q,          WQ_h + (0 * 3 + 2) * 16384, WQ_l + (0 * 3 + 2) * 16384, 128};
    tj.j[3]  = {qw_q + 16384,  WQ_h + (1 * 3 + 2) * 16384, WQ_l + (1 * 3 + 2) * 16384, 128};
    tj.j[4]  = {qw_a,          WA_h + (0 * 3 + 2) * 16384, WA_l + (0 * 3 + 2) * 16384, 128};
    tj.j[5]  = {qw_a + 16384,  WA_h + (1 * 3 + 2) * 16384, WA_l + (1 * 3 + 2) * 16384, 128};
    tj.j[6]  = {aw_q,          W_AQ_h,            W_AQ_l,            128};
    tj.j[7]  = {aw_q + 16384,  W_AQ_h + 16384,    W_AQ_l + 16384,    128};
    tj.j[8]  = {aw_a,          W_AA_h,            W_AA_l,            128};
    tj.j[9]  = {aw_a + 16384,  W_AA_h + 16384,    W_AA_l + 16384,    128};
    tj.j[10] = {lin_w,         W_LIN_h,           W_LIN_l,           64};
    prep_wt_all_k<<<dim3(64, 11), B, 0, stream>>>(tj);
    prep_fused_k<<<dim3(64, 8), B, 0, stream>>>(kw_q, kw_a, vw_q, vw_a, a_rel, m_rel,
                                                WQ_h, WQ_l, WA_h, WA_l);
    prep_bias_k<<<dim3(6), B, 0, stream>>>(kb_q, vb_q, qb_q, kb_a, vb_a, qb_a,
                                           a_rel, m_rel, BQ, BA);

    // CSR build
    int* degA = deg;        int* degB = deg + NM;
    int* curA = cursor;     int* curB = cursor + NM;
    int* incA = incl;       int* incB = incl + NM;
    int* bsA  = bsum;       int* bsB  = bsum + 256;
    int gEm = (EM + 255) / 256, gNm = (NM + 255) / 256;
    int gNa = (NA + 255) / 256, gNq = (NQ + 255) / 256;
    hipMemsetAsync(deg, 0, (size_t)2 * NM * 4, stream);
    hist2_k<<<dim3(gEm, 2), B, 0, stream>>>(ei_qa + Eqa, Eqa, degA, ei_aq + Eaq, Eaq, degB);
    scanA2_k<<<dim3(gNm, 2), B, 0, stream>>>(degA, incA, bsA, NA, degB, incB, bsB, NQ);
    scanB2_k<<<dim3(2), B, 0, stream>>>(bsA, gNa, bsB, gNq);
    scanC2_k<<<dim3(gNm, 2), B, 0, stream>>>(incA, degA, bsA, offs_a, curA, NA, Eqa,
                                             incB, degB, bsB, offs_q, curB, NQ, Eaq);
    scatter2_k<<<dim3(gEm, 2), B, 0, stream>>>(ei_qa, Eqa, curA, srcc_a,
                                               ei_aq, Eaq, curB, srcc_q);

    auto gx = [](int N, int ny) {
        int t = (N + 31) / 32; int cap = 1536 / ny;
        return (t < cap) ? t : cap;
    };

    // input projections + relu -> split planes
    gemm_regw_f32<<<dim3(gx(NQ, 1), 1), B, 0, stream>>>(
        x_q, W_LIN0Q_h, W_LIN0Q_l, lin0_bq, xq_hi, xq_lo, NQ);
    gemm_regw_f32<<<dim3(gx(NA, 1), 1), B, 0, stream>>>(
        x_a, W_LIN0A_h, W_LIN0A_l, lin0_ba, xa_hi, xa_lo, NA);

    for (int l = 0; l < 2; l++) {
        // xq -> [kt0 | vt0 | qdq]
        gemm_regw<128, 0, false, 1><<<dim3(gx(NQ, 3), 3), B, 0, stream>>>(
            xq_hi, xq_lo, WQ_h + l * 3 * 16384, WQ_l + l * 3 * 16384, BQ + l * 384,
            nullptr, nullptr, nullptr, kt0, vt0, qdq, nullptr, NQ);
        // xa -> [kt1 | vt1 | qda]
        gemm_regw<128, 0, false, 1><<<dim3(gx(NA, 3), 3), B, 0, stream>>>(
            xa_hi, xa_lo, WA_h + l * 3 * 16384, WA_l + l * 3 * 16384, BA + l * 384,
            nullptr, nullptr, nullptr, kt1, vt1, qda, nullptr, NA);
        // dir0: question -> answer
        edge_fused_k<<<dim3((NA + 3) / 4), B, 0, stream>>>(
            offs_a, srcc_a, kt0, vt0, qda, p_rel + (l * 2 + 0) * 8, ma_hi, ma_lo, NA);
        // dir1: answer -> question
        edge_fused_k<<<dim3((NQ + 3) / 4), B, 0, stream>>>(
            offs_q, srcc_q, kt1, vt1, qdq, p_rel + (l * 2 + 1) * 8, mq_hi, mq_lo, NQ);
        // output projections + gated skip (in-place on x planes)
        gemm_regw<128, 0, true, 2><<<dim3(gx(NQ, 1), 1), B, 0, stream>>>(
            mq_hi, mq_lo, W_AQ_h + l * 16384, W_AQ_l + l * 16384, ab_q + l * 128,
            xq_hi, xq_lo, skip_q + l, xq_hi, nullptr, nullptr, xq_lo, NQ);
        gemm_regw<128, 0, true, 2><<<dim3(gx(NA, 1), 1), B, 0, stream>>>(
            ma_hi, ma_lo, W_AA_h + l * 16384, W_AA_l + l * 16384, ab_a + l * 128,
            xa_hi, xa_lo, skip_a + l, xa_hi, nullptr, nullptr, xa_lo, NA);
    }

    // final linear over contiguous [xq|xa] -> d_out (f32)
    gemm_regw<64, 0, false, 0><<<dim3(gx(NQ + NA, 1), 1), B, 0, stream>>>(
        xhi, xlo, W_LIN_h, W_LIN_l, lin_b,
        nullptr, nullptr, nullptr, (float*)d_out, nullptr, nullptr, nullptr, NQ + NA);
}

// Round 7
// 571.447 us; speedup vs baseline: 3.0065x; 1.2202x over previous
//
#include <hip/hip_runtime.h>
#include <hip/hip_bf16.h>
#include <math.h>

typedef __attribute__((ext_vector_type(8))) short short8;
typedef __attribute__((ext_vector_type(4))) float f32x4;
typedef unsigned short u16;
typedef unsigned int u32;

// ---------- helpers ----------
__device__ __forceinline__ float bf2f(u16 u) {
    union { u32 i; float f; } x; x.i = ((u32)u) << 16; return x.f;
}
__device__ __forceinline__ u16 f2bf(float f) {
    union { float f; u32 i; } u; u.f = f;
    u32 r = u.i + 0x7fffu + ((u.i >> 16) & 1u);   // RNE
    return (u16)(r >> 16);
}
__device__ __forceinline__ float dotpair(u32 a, u32 b) {
    union { u32 i; float f; } alo, ahi, blo, bhi;
    alo.i = a << 16; ahi.i = a & 0xffff0000u;
    blo.i = b << 16; bhi.i = b & 0xffff0000u;
    return alo.f * blo.f + ahi.f * bhi.f;
}
// swizzled W layout: fragment-major; lane reads frag at ((wslot*4+ks)*512 + kg*128 + lr*8)
__device__ __forceinline__ int swz_idx(int m, int k) {
    return ((((m >> 4) * 4 + (k >> 5)) * 4 + ((k >> 3) & 3)) * 16 + (m & 15)) * 8 + (k & 7);
}

// ---------- batched weight prep (writes swizzled hi/lo) ----------
struct TJob { const float* src; u16* hi; u16* lo; int M; };
struct TJobs { TJob j[11]; };

__global__ void prep_wt_all_k(TJobs jobs) {
    TJob t = jobs.j[blockIdx.y];
    int idx = blockIdx.x * 256 + threadIdx.x;
    if (idx >= t.M * 128) return;
    int m = idx >> 7, k = idx & 127;
    float w = t.src[k * t.M + m];
    u16 h = f2bf(w);
    int o = swz_idx(m, k);
    t.hi[o] = h;
    t.lo[o] = f2bf(w - bf2f(h));
}

// fused (w @ blockdiag(rel)) -> WQ[l][kv] / WA[l][kv] chunks (swizzled)
__global__ void prep_fused_k(const float* kw_q, const float* kw_a,
                             const float* vw_q, const float* vw_a,
                             const float* a_rel, const float* m_rel,
                             u16* WQh, u16* WQl, u16* WAh, u16* WAl) {
    int j = blockIdx.y;
    int l = j >> 2, dir = (j >> 1) & 1, kv = j & 1;
    const float* w = kv ? (dir ? vw_a : vw_q) : (dir ? kw_a : kw_q);
    w += l * 16384;
    const float* rel = (kv ? m_rel : a_rel) + (l * 2 + dir) * 2048;
    u16* dhi = (dir ? WAh : WQh) + (l * 3 + kv) * 16384;
    u16* dlo = (dir ? WAl : WQl) + (l * 3 + kv) * 16384;
    int idx = blockIdx.x * 256 + threadIdx.x;       // 16384
    int m = idx >> 7, k = idx & 127;
    int h = m >> 4, f = m & 15;
    float s = 0.f;
#pragma unroll
    for (int d = 0; d < 16; d++)
        s += w[k * 128 + h * 16 + d] * rel[(h * 16 + d) * 16 + f];
    u16 hh = f2bf(s);
    int o = swz_idx(m, k);
    dhi[o] = hh;
    dlo[o] = f2bf(s - bf2f(hh));
}

// BQ[2][384], BA[2][384] (f32): [fused kb | fused vb | qb]
__global__ void prep_bias_k(const float* kb_q, const float* vb_q, const float* qb_q,
                            const float* kb_a, const float* vb_a, const float* qb_a,
                            const float* a_rel, const float* m_rel,
                            float* BQ, float* BA) {
    int idx = blockIdx.x * 256 + threadIdx.x;
    if (idx >= 1536) return;
    int side = idx / 768, r = idx % 768;
    int l = r / 384, m = r % 384;
    float* dst = side ? BA : BQ;
    if (m >= 256) {
        const float* qb = side ? qb_a : qb_q;
        dst[l * 384 + m] = qb[l * 128 + (m - 256)];
        return;
    }
    int kv = m >> 7, mc = m & 127, h = mc >> 4, f = mc & 15;
    const float* b = side ? (kv ? vb_a : kb_a) : (kv ? vb_q : kb_q);
    b += l * 128;
    const float* rel = (kv ? m_rel : a_rel) + (l * 2 + side) * 2048;
    float s = 0.f;
#pragma unroll
    for (int d = 0; d < 16; d++) s += b[h * 16 + d] * rel[(h * 16 + d) * 16 + f];
    dst[l * 384 + m] = s;
}

// ---------- batched CSR build (y = edge-set index) ----------
__global__ void hist2_k(const int* dA, int Ea, int* degA,
                        const int* dB, int Eb, int* degB) {
    int y = blockIdx.y;
    const int* dst = y ? dB : dA; int E = y ? Eb : Ea; int* deg = y ? degB : degA;
    int i = blockIdx.x * 256 + threadIdx.x;
    if (i < E) atomicAdd(&deg[dst[i]], 1);
}
__global__ void scanA2_k(const int* degA, int* inclA, int* bsumA, int nA,
                         const int* degB, int* inclB, int* bsumB, int nB) {
    int y = blockIdx.y;
    const int* deg = y ? degB : degA; int* incl = y ? inclB : inclA;
    int* bsum = y ? bsumB : bsumA; int n = y ? nB : nA;
    __shared__ int s[256];
    int i = blockIdx.x * 256 + threadIdx.x;
    int v = (i < n) ? deg[i] : 0;
    s[threadIdx.x] = v;
    __syncthreads();
    for (int off = 1; off < 256; off <<= 1) {
        int t = (threadIdx.x >= off) ? s[threadIdx.x - off] : 0;
        __syncthreads();
        s[threadIdx.x] += t;
        __syncthreads();
    }
    if (i < n) incl[i] = s[threadIdx.x];
    if (threadIdx.x == 255) bsum[blockIdx.x] = s[255];
}
__global__ void scanB2_k(int* bsumA, int nbA, int* bsumB, int nbB) {
    int* bsum = blockIdx.x ? bsumB : bsumA;
    int nb = blockIdx.x ? nbB : nbA;
    __shared__ int s[256];
    int v = (threadIdx.x < nb) ? bsum[threadIdx.x] : 0;
    s[threadIdx.x] = v;
    __syncthreads();
    for (int off = 1; off < 256; off <<= 1) {
        int t = (threadIdx.x >= off) ? s[threadIdx.x - off] : 0;
        __syncthreads();
        s[threadIdx.x] += t;
        __syncthreads();
    }
    if (threadIdx.x < nb) bsum[threadIdx.x] = s[threadIdx.x] - v;  // exclusive
}
__global__ void scanC2_k(const int* inclA, const int* degA, const int* bsumA,
                         int* offsA, int* curA, int nA, int Ea,
                         const int* inclB, const int* degB, const int* bsumB,
                         int* offsB, int* curB, int nB, int Eb) {
    int y = blockIdx.y;
    const int* incl = y ? inclB : inclA; const int* deg = y ? degB : degA;
    const int* bsum = y ? bsumB : bsumA;
    int* offs = y ? offsB : offsA; int* cur = y ? curB : curA;
    int n = y ? nB : nA; int E = y ? Eb : Ea;
    int i = blockIdx.x * 256 + threadIdx.x;
    if (i < n) {
        int o = incl[i] - deg[i] + bsum[blockIdx.x];
        offs[i] = o;
        cur[i] = o;
    }
    if (i == 0) offs[n] = E;
}
__global__ void scatter2_k(const int* eiA, int Ea, int* curA, int* srccA,
                           const int* eiB, int Eb, int* curB, int* srccB) {
    int y = blockIdx.y;
    const int* ei = y ? eiB : eiA; int E = y ? Eb : Ea;
    int* cur = y ? curB : curA; int* srcc = y ? srccB : srccA;
    int e = blockIdx.x * 256 + threadIdx.x;
    if (e < E) {
        int p = atomicAdd(&cur[ei[E + e]], 1);   // dst row
        srcc[p] = ei[e];                          // src id in CSR order
    }
}

// ---------- fused edge phase (both directions in one dispatch via blockIdx.y) ----------
struct EJob {
    const int* offs; const int* srcc;
    const u16* kt; const u16* vt; const u16* qd;
    const float* pr;
    u16* mhi; u16* mlo; int n;
};
struct EJobs { EJob j[2]; };

__global__ __launch_bounds__(256) void edge_fused_k(EJobs jobs) {
    EJob J = jobs.j[blockIdx.y];
    int lane = threadIdx.x & 63;
    int node = blockIdx.x * 4 + (threadIdx.x >> 6);
    if (node >= J.n) return;
    int s0 = J.offs[node], s1 = J.offs[node + 1];
    int h = lane & 7, jj = lane >> 3;
    int hc = lane >> 3;                 // head of this lane's channel pair

    float accx = 0.f, accy = 0.f;
    float m = -INFINITY, den = 0.f;

    if (s0 < s1) {
        const u16* qrow = J.qd + (size_t)node * 128 + h * 16;
        uint4 q0 = *(const uint4*)qrow;
        uint4 q1 = *(const uint4*)(qrow + 8);
        float prh = J.pr[h] * 0.25f;    // SCALE = 1/sqrt(16)

        int jf = s0 + jj;
        int src_next = J.srcc[(jf < s1) ? jf : (s1 - 1)];
        for (int base = s0; base < s1; base += 8) {
            int cnt = s1 - base; if (cnt > 8) cnt = 8;
            int src = src_next;
            if (base + 8 < s1) {                    // prefetch next chunk's src ids
                int jn = base + 8 + jj;
                src_next = J.srcc[(jn < s1) ? jn : (s1 - 1)];
            }
            const u16* krow = J.kt + (size_t)src * 128 + h * 16;
            uint4 k0 = *(const uint4*)krow;
            uint4 k1 = *(const uint4*)(krow + 8);
            float a = dotpair(k0.x, q0.x) + dotpair(k0.y, q0.y)
                    + dotpair(k0.z, q0.z) + dotpair(k0.w, q0.w)
                    + dotpair(k1.x, q1.x) + dotpair(k1.y, q1.y)
                    + dotpair(k1.z, q1.z) + dotpair(k1.w, q1.w);
            a = (jj < cnt) ? a * prh : -INFINITY;

            float cm = a;
            cm = fmaxf(cm, __shfl_xor(cm, 8));
            cm = fmaxf(cm, __shfl_xor(cm, 16));
            cm = fmaxf(cm, __shfl_xor(cm, 32));
            float mn = fmaxf(m, cm);
            float scale = __expf(m - mn);
            float p = __expf(a - mn);
            float ps = p;
            ps += __shfl_xor(ps, 8);
            ps += __shfl_xor(ps, 16);
            ps += __shfl_xor(ps, 32);
            den = den * scale + ps;
            m = mn;

            // gather all V rows first (MLP), then weight-and-accumulate
            u32 vv[8];
#pragma unroll
            for (int t = 0; t < 8; t++) {
                int s2 = __shfl(src, t * 8);
                vv[t] = (t < cnt) ? *(const u32*)(J.vt + (size_t)s2 * 128 + lane * 2) : 0u;
            }
            float sc = __shfl(scale, hc);
            accx *= sc; accy *= sc;
#pragma unroll
            for (int t = 0; t < 8; t++) {
                float w = __shfl(p, t * 8 + hc);     // 0 for invalid lanes
                accx += w * bf2f((u16)(vv[t] & 0xffffu));
                accy += w * bf2f((u16)(vv[t] >> 16));
            }
        }
    }

    float dc = __shfl(den, hc);
    float inv = (dc > 0.f) ? (1.f / dc) : 0.f;
    float vx = accx * inv, vy = accy * inv;
    vx = 0.5f * vx * (1.f + erff(vx * 0.70710678118654752f));
    vy = 0.5f * vy * (1.f + erff(vy * 0.70710678118654752f));
    u16 hx = f2bf(vx), hy = f2bf(vy);
    u16 lx = f2bf(vx - bf2f(hx)), ly = f2bf(vy - bf2f(hy));
    size_t ob = (size_t)node * 128 + lane * 2;
    *(u32*)(J.mhi + ob) = (u32)hx | ((u32)hy << 16);
    *(u32*)(J.mlo + ob) = (u32)lx | ((u32)ly << 16);
}

// ---------- register-W GEMM family ----------
// Each wave owns 32 cols of W in VGPRs (pre-swizzled). 16 rows/tile, grid-stride.
// No LDS, no barriers. 3-MFMA bf16 split => ~f32 accuracy. ~110 VGPR -> 4 waves/SIMD.

// projection: bf16-plane A -> single bf16 out, 6 jobs via blockIdx.y
struct GJob { const u16* xhi; const u16* xlo; const u16* wh; const u16* wl;
              const float* bias; u16* y; int N; };
struct GJobs { GJob j[6]; };

__global__ __launch_bounds__(256, 4) void gemm_proj_k(GJobs jobs) {
    GJob J = jobs.j[blockIdx.y];
    int tid = threadIdx.x;
    int wave = tid >> 6, lane = tid & 63;
    int lr = lane & 15, kg = lane >> 4;

    short8 wh[2][4], wl[2][4];
#pragma unroll
    for (int ct = 0; ct < 2; ct++)
#pragma unroll
        for (int ks = 0; ks < 4; ks++) {
            int o = ((wave * 2 + ct) * 4 + ks) * 512 + kg * 128 + lr * 8;
            wh[ct][ks] = *(const short8*)(J.wh + o);
            wl[ct][ks] = *(const short8*)(J.wl + o);
        }

    int ntiles = (J.N + 15) >> 4;
    for (int t = blockIdx.x; t < ntiles; t += gridDim.x) {
        int arow = t * 16 + lr;
        if (arow >= J.N) arow = J.N - 1;
        const u16* ph = J.xhi + (size_t)arow * 128 + kg * 8;
        const u16* pl = J.xlo + (size_t)arow * 128 + kg * 8;
        short8 ahi[4], alo[4];
#pragma unroll
        for (int ks = 0; ks < 4; ks++) {
            ahi[ks] = *(const short8*)(ph + ks * 32);
            alo[ks] = *(const short8*)(pl + ks * 32);
        }
        f32x4 acc[2] = {f32x4{0.f, 0.f, 0.f, 0.f}, f32x4{0.f, 0.f, 0.f, 0.f}};
#pragma unroll
        for (int ks = 0; ks < 4; ks++)
#pragma unroll
            for (int ct = 0; ct < 2; ct++) {
                acc[ct] = __builtin_amdgcn_mfma_f32_16x16x32_bf16(ahi[ks], wh[ct][ks], acc[ct], 0, 0, 0);
                acc[ct] = __builtin_amdgcn_mfma_f32_16x16x32_bf16(alo[ks], wh[ct][ks], acc[ct], 0, 0, 0);
                acc[ct] = __builtin_amdgcn_mfma_f32_16x16x32_bf16(ahi[ks], wl[ct][ks], acc[ct], 0, 0, 0);
            }
        int crow0 = t * 16 + kg * 4;
#pragma unroll
        for (int ct = 0; ct < 2; ct++) {
            int col = (wave * 2 + ct) * 16 + lr;
            float bcol = J.bias[col];
#pragma unroll
            for (int r = 0; r < 4; r++) {
                int gr = crow0 + r;
                if (gr < J.N) J.y[(size_t)gr * 128 + col] = f2bf(acc[ct][r] + bcol);
            }
        }
    }
}

// skip GEMM: msg planes -> gated mix with x planes, split-plane out (in place), 2 jobs
struct SJob { const u16* mhi; const u16* mlo; const u16* wh; const u16* wl;
              const float* bias; u16* xhi; u16* xlo; const float* gate; int N; };
struct SJobs { SJob j[2]; };

__global__ __launch_bounds__(256, 3) void gemm_skip_k(SJobs jobs) {
    SJob J = jobs.j[blockIdx.y];
    int tid = threadIdx.x;
    int wave = tid >> 6, lane = tid & 63;
    int lr = lane & 15, kg = lane >> 4;

    short8 wh[2][4], wl[2][4];
#pragma unroll
    for (int ct = 0; ct < 2; ct++)
#pragma unroll
        for (int ks = 0; ks < 4; ks++) {
            int o = ((wave * 2 + ct) * 4 + ks) * 512 + kg * 128 + lr * 8;
            wh[ct][ks] = *(const short8*)(J.wh + o);
            wl[ct][ks] = *(const short8*)(J.wl + o);
        }
    float gk = J.gate[0];
    float g = 1.f / (1.f + __expf(-gk));
    float gi = 1.f - g;

    int ntiles = (J.N + 15) >> 4;
    for (int t = blockIdx.x; t < ntiles; t += gridDim.x) {
        int arow = t * 16 + lr;
        if (arow >= J.N) arow = J.N - 1;
        const u16* ph = J.mhi + (size_t)arow * 128 + kg * 8;
        const u16* pl = J.mlo + (size_t)arow * 128 + kg * 8;
        short8 ahi[4], alo[4];
#pragma unroll
        for (int ks = 0; ks < 4; ks++) {
            ahi[ks] = *(const short8*)(ph + ks * 32);
            alo[ks] = *(const short8*)(pl + ks * 32);
        }
        f32x4 acc[2] = {f32x4{0.f, 0.f, 0.f, 0.f}, f32x4{0.f, 0.f, 0.f, 0.f}};
#pragma unroll
        for (int ks = 0; ks < 4; ks++)
#pragma unroll
            for (int ct = 0; ct < 2; ct++) {
                acc[ct] = __builtin_amdgcn_mfma_f32_16x16x32_bf16(ahi[ks], wh[ct][ks], acc[ct], 0, 0, 0);
                acc[ct] = __builtin_amdgcn_mfma_f32_16x16x32_bf16(alo[ks], wh[ct][ks], acc[ct], 0, 0, 0);
                acc[ct] = __builtin_amdgcn_mfma_f32_16x16x32_bf16(ahi[ks], wl[ct][ks], acc[ct], 0, 0, 0);
            }
        int crow0 = t * 16 + kg * 4;
#pragma unroll
        for (int ct = 0; ct < 2; ct++) {
            int col = (wave * 2 + ct) * 16 + lr;
            float bcol = J.bias[col];
#pragma unroll
            for (int r = 0; r < 4; r++) {
                int gr = crow0 + r;
                if (gr < J.N) {
                    size_t si = (size_t)gr * 128 + col;
                    float v = acc[ct][r] + bcol;
                    v = g * v + gi * (bf2f(J.xhi[si]) + bf2f(J.xlo[si]));
                    u16 hv = f2bf(v);
                    J.xhi[si] = hv;
                    J.xlo[si] = f2bf(v - bf2f(hv));
                }
            }
        }
    }
}

// input projection: f32 A + relu -> split planes, 2 jobs
struct FJob { const float* x; const u16* wh; const u16* wl; const float* bias;
              u16* yhi; u16* ylo; int N; };
struct FJobs { FJob j[2]; };

__global__ __launch_bounds__(256, 3) void gemm_in_k(FJobs jobs) {
    FJob J = jobs.j[blockIdx.y];
    int tid = threadIdx.x;
    int wave = tid >> 6, lane = tid & 63;
    int lr = lane & 15, kg = lane >> 4;

    short8 wh[2][4], wl[2][4];
#pragma unroll
    for (int ct = 0; ct < 2; ct++)
#pragma unroll
        for (int ks = 0; ks < 4; ks++) {
            int o = ((wave * 2 + ct) * 4 + ks) * 512 + kg * 128 + lr * 8;
            wh[ct][ks] = *(const short8*)(J.wh + o);
            wl[ct][ks] = *(const short8*)(J.wl + o);
        }

    int ntiles = (J.N + 15) >> 4;
    for (int t = blockIdx.x; t < ntiles; t += gridDim.x) {
        int arow = t * 16 + lr;
        if (arow >= J.N) arow = J.N - 1;
        const float* p = J.x + (size_t)arow * 128 + kg * 8;
        short8 ahi[4], alo[4];
#pragma unroll
        for (int ks = 0; ks < 4; ks++) {
            float4 v0 = *(const float4*)(p + ks * 32);
            float4 v1 = *(const float4*)(p + ks * 32 + 4);
            float a8[8] = {v0.x, v0.y, v0.z, v0.w, v1.x, v1.y, v1.z, v1.w};
#pragma unroll
            for (int j = 0; j < 8; j++) {
                u16 h = f2bf(a8[j]);
                ahi[ks][j] = (short)h;
                alo[ks][j] = (short)f2bf(a8[j] - bf2f(h));
            }
        }
        f32x4 acc[2] = {f32x4{0.f, 0.f, 0.f, 0.f}, f32x4{0.f, 0.f, 0.f, 0.f}};
#pragma unroll
        for (int ks = 0; ks < 4; ks++)
#pragma unroll
            for (int ct = 0; ct < 2; ct++) {
                acc[ct] = __builtin_amdgcn_mfma_f32_16x16x32_bf16(ahi[ks], wh[ct][ks], acc[ct], 0, 0, 0);
                acc[ct] = __builtin_amdgcn_mfma_f32_16x16x32_bf16(alo[ks], wh[ct][ks], acc[ct], 0, 0, 0);
                acc[ct] = __builtin_amdgcn_mfma_f32_16x16x32_bf16(ahi[ks], wl[ct][ks], acc[ct], 0, 0, 0);
            }
        int crow0 = t * 16 + kg * 4;
#pragma unroll
        for (int ct = 0; ct < 2; ct++) {
            int col = (wave * 2 + ct) * 16 + lr;
            float bcol = J.bias[col];
#pragma unroll
            for (int r = 0; r < 4; r++) {
                int gr = crow0 + r;
                if (gr < J.N) {
                    float v = fmaxf(acc[ct][r] + bcol, 0.f);
                    u16 hv = f2bf(v);
                    size_t si = (size_t)gr * 128 + col;
                    J.yhi[si] = hv;
                    J.ylo[si] = f2bf(v - bf2f(hv));
                }
            }
        }
    }
}

// final linear: plane A -> f32 out, MOUT=64
__global__ __launch_bounds__(256, 4) void gemm_fin_k(
    const u16* __restrict__ Xhi, const u16* __restrict__ Xlo,
    const u16* __restrict__ Wh, const u16* __restrict__ Wl,
    const float* __restrict__ bias, float* __restrict__ Y, int N) {
    int tid = threadIdx.x;
    int wave = tid >> 6, lane = tid & 63;
    int lr = lane & 15, kg = lane >> 4;

    short8 wh[4], wl[4];
#pragma unroll
    for (int ks = 0; ks < 4; ks++) {
        int o = (wave * 4 + ks) * 512 + kg * 128 + lr * 8;
        wh[ks] = *(const short8*)(Wh + o);
        wl[ks] = *(const short8*)(Wl + o);
    }

    int ntiles = (N + 15) >> 4;
    for (int t = blockIdx.x; t < ntiles; t += gridDim.x) {
        int arow = t * 16 + lr;
        if (arow >= N) arow = N - 1;
        const u16* ph = Xhi + (size_t)arow * 128 + kg * 8;
        const u16* pl = Xlo + (size_t)arow * 128 + kg * 8;
        short8 ahi[4], alo[4];
#pragma unroll
        for (int ks = 0; ks < 4; ks++) {
            ahi[ks] = *(const short8*)(ph + ks * 32);
            alo[ks] = *(const short8*)(pl + ks * 32);
        }
        f32x4 acc = f32x4{0.f, 0.f, 0.f, 0.f};
#pragma unroll
        for (int ks = 0; ks < 4; ks++) {
            acc = __builtin_amdgcn_mfma_f32_16x16x32_bf16(ahi[ks], wh[ks], acc, 0, 0, 0);
            acc = __builtin_amdgcn_mfma_f32_16x16x32_bf16(alo[ks], wh[ks], acc, 0, 0, 0);
            acc = __builtin_amdgcn_mfma_f32_16x16x32_bf16(ahi[ks], wl[ks], acc, 0, 0, 0);
        }
        int crow0 = t * 16 + kg * 4;
        int col = wave * 16 + lr;
        float bcol = bias[col];
#pragma unroll
        for (int r = 0; r < 4; r++) {
            int gr = crow0 + r;
            if (gr < N) Y[(size_t)gr * 64 + col] = acc[r] + bcol;
        }
    }
}

// ---------- launch ----------
extern "C" void kernel_launch(void* const* d_in, const int* in_sizes, int n_in,
                              void* d_out, int out_size, void* d_ws, size_t ws_size,
                              hipStream_t stream) {
    const int NQ = in_sizes[0] / 128;
    const int NA = in_sizes[1] / 128;
    const int Eqa = in_sizes[29] / 2;
    const int Eaq = in_sizes[30] / 2;
    const int NM = (NQ > NA) ? NQ : NA;
    const int EM = (Eqa > Eaq) ? Eqa : Eaq;

    const float* x_q     = (const float*)d_in[0];
    const float* x_a     = (const float*)d_in[1];
    const float* lin0_wq = (const float*)d_in[2];
    const float* lin0_bq = (const float*)d_in[3];
    const float* lin0_wa = (const float*)d_in[4];
    const float* lin0_ba = (const float*)d_in[5];
    const float* kw_q = (const float*)d_in[6];
    const float* kb_q = (const float*)d_in[7];
    const float* qw_q = (const float*)d_in[8];
    const float* qb_q = (const float*)d_in[9];
    const float* vw_q = (const float*)d_in[10];
    const float* vb_q = (const float*)d_in[11];
    const float* aw_q = (const float*)d_in[12];
    const float* ab_q = (const float*)d_in[13];
    const float* kw_a = (const float*)d_in[14];
    const float* kb_a = (const float*)d_in[15];
    const float* qw_a = (const float*)d_in[16];
    const float* qb_a = (const float*)d_in[17];
    const float* vw_a = (const float*)d_in[18];
    const float* vb_a = (const float*)d_in[19];
    const float* aw_a = (const float*)d_in[20];
    const float* ab_a = (const float*)d_in[21];
    const float* skip_q = (const float*)d_in[22];
    const float* skip_a = (const float*)d_in[23];
    const float* a_rel = (const float*)d_in[24];
    const float* m_rel = (const float*)d_in[25];
    const float* p_rel = (const float*)d_in[26];
    const float* lin_w = (const float*)d_in[27];
    const float* lin_b = (const float*)d_in[28];
    const int* ei_qa = (const int*)d_in[29];
    const int* ei_aq = (const int*)d_in[30];

    // ---- workspace ----
    size_t off = 0;
    auto alloc = [&](size_t bytes) -> void* {
        void* p = (char*)d_ws + off;
        off += (bytes + 255) & ~(size_t)255;
        return p;
    };
    u16* xhi = (u16*)alloc((size_t)(NQ + NA) * 128 * 2);   // rows [0,NQ)=q, rest=a
    u16* xlo = (u16*)alloc((size_t)(NQ + NA) * 128 * 2);
    u16* xq_hi = xhi;            u16* xq_lo = xlo;
    u16* xa_hi = xhi + (size_t)NQ * 128;
    u16* xa_lo = xlo + (size_t)NQ * 128;
    u16* mq_hi = (u16*)alloc((size_t)NQ * 128 * 2);
    u16* mq_lo = (u16*)alloc((size_t)NQ * 128 * 2);
    u16* ma_hi = (u16*)alloc((size_t)NA * 128 * 2);
    u16* ma_lo = (u16*)alloc((size_t)NA * 128 * 2);
    u16* kt0 = (u16*)alloc((size_t)NM * 128 * 2);
    u16* vt0 = (u16*)alloc((size_t)NM * 128 * 2);
    u16* qdq = (u16*)alloc((size_t)NM * 128 * 2);
    u16* kt1 = (u16*)alloc((size_t)NM * 128 * 2);
    u16* vt1 = (u16*)alloc((size_t)NM * 128 * 2);
    u16* qda = (u16*)alloc((size_t)NM * 128 * 2);
    int* offs_a = (int*)alloc((size_t)(NA + 1) * 4);
    int* offs_q = (int*)alloc((size_t)(NQ + 1) * 4);
    int* srcc_a = (int*)alloc((size_t)Eqa * 4);
    int* srcc_q = (int*)alloc((size_t)Eaq * 4);
    int* deg    = (int*)alloc((size_t)2 * NM * 4);
    int* cursor = (int*)alloc((size_t)2 * NM * 4);
    int* incl   = (int*)alloc((size_t)2 * NM * 4);
    int* bsum   = (int*)alloc(2048);
    u16* W_LIN0Q_h = (u16*)alloc(16384 * 2); u16* W_LIN0Q_l = (u16*)alloc(16384 * 2);
    u16* W_LIN0A_h = (u16*)alloc(16384 * 2); u16* W_LIN0A_l = (u16*)alloc(16384 * 2);
    u16* WQ_h = (u16*)alloc(2 * 3 * 16384 * 2); u16* WQ_l = (u16*)alloc(2 * 3 * 16384 * 2);
    u16* WA_h = (u16*)alloc(2 * 3 * 16384 * 2); u16* WA_l = (u16*)alloc(2 * 3 * 16384 * 2);
    u16* W_AQ_h = (u16*)alloc(2 * 16384 * 2); u16* W_AQ_l = (u16*)alloc(2 * 16384 * 2);
    u16* W_AA_h = (u16*)alloc(2 * 16384 * 2); u16* W_AA_l = (u16*)alloc(2 * 16384 * 2);
    u16* W_LIN_h = (u16*)alloc(8192 * 2);     u16* W_LIN_l = (u16*)alloc(8192 * 2);
    float* BQ = (float*)alloc(2 * 384 * 4);
    float* BA = (float*)alloc(2 * 384 * 4);
    (void)ws_size; (void)n_in; (void)out_size; (void)EM;

    dim3 B(256);

    // weight prep
    TJobs tj;
    tj.j[0]  = {lin0_wq, W_LIN0Q_h, W_LIN0Q_l, 128};
    tj.j[1]  = {lin0_wa, W_LIN0A_h, W_LIN0A_l, 128};
    tj.j[2]  = {qw_q,          WQ_h + (0 * 3 + 2) * 16384, WQ_l + (0 * 3 + 2) * 16384, 128};
    tj.j[3]  = {qw_q + 16384,  WQ_h + (1 * 3 + 2) * 16384, WQ_l + (1 * 3 + 2) * 16384, 128};
    tj.j[4]  = {qw_a,          WA_h + (0 * 3 + 2) * 16384, WA_l + (0 * 3 + 2) * 16384, 128};
    tj.j[5]  = {qw_a + 16384,  WA_h + (1 * 3 + 2) * 16384, WA_l + (1 * 3 + 2) * 16384, 128};
    tj.j[6]  = {aw_q,          W_AQ_h,            W_AQ_l,            128};
    tj.j[7]  = {aw_q + 16384,  W_AQ_h + 16384,    W_AQ_l + 16384,    128};
    tj.j[8]  = {aw_a,          W_AA_h,            W_AA_l,            128};
    tj.j[9]  = {aw_a + 16384,  W_AA_h + 16384,    W_AA_l + 16384,    128};
    tj.j[10] = {lin_w,         W_LIN_h,           W_LIN_l,           64};
    prep_wt_all_k<<<dim3(64, 11), B, 0, stream>>>(tj);
    prep_fused_k<<<dim3(64, 8), B, 0, stream>>>(kw_q, kw_a, vw_q, vw_a, a_rel, m_rel,
                                                WQ_h, WQ_l, WA_h, WA_l);
    prep_bias_k<<<dim3(6), B, 0, stream>>>(kb_q, vb_q, qb_q, kb_a, vb_a, qb_a,
                                           a_rel, m_rel, BQ, BA);

    // CSR build
    int* degA = deg;        int* degB = deg + NM;
    int* curA = cursor;     int* curB = cursor + NM;
    int* incA = incl;       int* incB = incl + NM;
    int* bsA  = bsum;       int* bsB  = bsum + 256;
    int gEm = (EM + 255) / 256, gNm = (NM + 255) / 256;
    int gNa = (NA + 255) / 256, gNq = (NQ + 255) / 256;
    hipMemsetAsync(deg, 0, (size_t)2 * NM * 4, stream);
    hist2_k<<<dim3(gEm, 2), B, 0, stream>>>(ei_qa + Eqa, Eqa, degA, ei_aq + Eaq, Eaq, degB);
    scanA2_k<<<dim3(gNm, 2), B, 0, stream>>>(degA, incA, bsA, NA, degB, incB, bsB, NQ);
    scanB2_k<<<dim3(2), B, 0, stream>>>(bsA, gNa, bsB, gNq);
    scanC2_k<<<dim3(gNm, 2), B, 0, stream>>>(incA, degA, bsA, offs_a, curA, NA, Eqa,
                                             incB, degB, bsB, offs_q, curB, NQ, Eaq);
    scatter2_k<<<dim3(gEm, 2), B, 0, stream>>>(ei_qa, Eqa, curA, srcc_a,
                                               ei_aq, Eaq, curB, srcc_q);

    // input projections + relu -> split planes (one dispatch, 2 jobs)
    {
        FJobs fj;
        fj.j[0] = {x_q, W_LIN0Q_h, W_LIN0Q_l, lin0_bq, xq_hi, xq_lo, NQ};
        fj.j[1] = {x_a, W_LIN0A_h, W_LIN0A_l, lin0_ba, xa_hi, xa_lo, NA};
        gemm_in_k<<<dim3(512, 2), B, 0, stream>>>(fj);
    }

    for (int l = 0; l < 2; l++) {
        // all 6 projection chunks in one dispatch
        GJobs gj;
        gj.j[0] = {xq_hi, xq_lo, WQ_h + (l * 3 + 0) * 16384, WQ_l + (l * 3 + 0) * 16384, BQ + l * 384 + 0,   kt0, NQ};
        gj.j[1] = {xq_hi, xq_lo, WQ_h + (l * 3 + 1) * 16384, WQ_l + (l * 3 + 1) * 16384, BQ + l * 384 + 128, vt0, NQ};
        gj.j[2] = {xq_hi, xq_lo, WQ_h + (l * 3 + 2) * 16384, WQ_l + (l * 3 + 2) * 16384, BQ + l * 384 + 256, qdq, NQ};
        gj.j[3] = {xa_hi, xa_lo, WA_h + (l * 3 + 0) * 16384, WA_l + (l * 3 + 0) * 16384, BA + l * 384 + 0,   kt1, NA};
        gj.j[4] = {xa_hi, xa_lo, WA_h + (l * 3 + 1) * 16384, WA_l + (l * 3 + 1) * 16384, BA + l * 384 + 128, vt1, NA};
        gj.j[5] = {xa_hi, xa_lo, WA_h + (l * 3 + 2) * 16384, WA_l + (l * 3 + 2) * 16384, BA + l * 384 + 256, qda, NA};
        gemm_proj_k<<<dim3(512, 6), B, 0, stream>>>(gj);

        // both edge directions in one dispatch
        EJobs ej;
        ej.j[0] = {offs_a, srcc_a, kt0, vt0, qda, p_rel + (l * 2 + 0) * 8, ma_hi, ma_lo, NA};
        ej.j[1] = {offs_q, srcc_q, kt1, vt1, qdq, p_rel + (l * 2 + 1) * 8, mq_hi, mq_lo, NQ};
        edge_fused_k<<<dim3((NM + 3) / 4, 2), B, 0, stream>>>(ej);

        // both skip GEMMs in one dispatch (in-place on x planes)
        SJobs sj;
        sj.j[0] = {mq_hi, mq_lo, W_AQ_h + l * 16384, W_AQ_l + l * 16384, ab_q + l * 128,
                   xq_hi, xq_lo, skip_q + l, NQ};
        sj.j[1] = {ma_hi, ma_lo, W_AA_h + l * 16384, W_AA_l + l * 16384, ab_a + l * 128,
                   xa_hi, xa_lo, skip_a + l, NA};
        gemm_skip_k<<<dim3(512, 2), B, 0, stream>>>(sj);
    }

    // final linear over contiguous [xq|xa] -> d_out (f32)
    gemm_fin_k<<<dim3(1024, 1), B, 0, stream>>>(
        xhi, xlo, W_LIN_h, W_LIN_l, lin_b, (float*)d_out, NQ + NA);
}